// Round 9
// baseline (365.133 us; speedup 1.0000x reference)
//
#include <hip/hip_runtime.h>
#include <hip/hip_fp16.h>
#include <math.h>

#define NODES 50000
#define EDGES 800000
#define NB_SCAN ((NODES + 1023) / 1024)

typedef __attribute__((ext_vector_type(8))) _Float16 f16x8;
typedef __attribute__((ext_vector_type(4))) _Float16 f16x4;
typedef __attribute__((ext_vector_type(4))) float f32x4;

__device__ __forceinline__ float lrelu02(float x){ return x > 0.f ? x : 0.2f * x; }

__device__ __forceinline__ f32x4 shflx4(f32x4 v, int m){
  f32x4 r;
  r[0] = __shfl_xor(v[0], m); r[1] = __shfl_xor(v[1], m);
  r[2] = __shfl_xor(v[2], m); r[3] = __shfl_xor(v[3], m);
  return r;
}

// ---------------- CSR build ----------------

__global__ __launch_bounds__(256) void gat_hist(const int* __restrict__ ei, int* __restrict__ cnt){
  int e = blockIdx.x * 256 + threadIdx.x;
  if (e < EDGES) atomicAdd(&cnt[ei[EDGES + e]], 1);
}

__global__ __launch_bounds__(256) void gat_blocksum(const int* __restrict__ cnt, int* __restrict__ bsums){
  __shared__ int sd[256];
  int t = threadIdx.x, b = blockIdx.x;
  int base = b * 1024 + t * 4, s = 0;
  #pragma unroll
  for (int j = 0; j < 4; j++){ int i = base + j; if (i < NODES) s += cnt[i]; }
  sd[t] = s; __syncthreads();
  for (int o = 128; o > 0; o >>= 1){ if (t < o) sd[t] += sd[t + o]; __syncthreads(); }
  if (t == 0) bsums[b] = sd[0];
}

// rowptr with inline serial scan of bsums (<=48 adds from L2 per block)
__global__ __launch_bounds__(256) void gat_rowptr(int* __restrict__ cnt, const int* __restrict__ bsums,
                                                  int* __restrict__ row_ptr){
  __shared__ int sd[256];
  int t = threadIdx.x, b = blockIdx.x;
  int base = b * 1024 + t * 4;
  int c[4]; int s = 0;
  #pragma unroll
  for (int j = 0; j < 4; j++){
    int i = base + j;
    c[j] = (i < NODES) ? cnt[i] : 0;
    s += c[j];
    if (i < NODES) cnt[i] = 0;
  }
  sd[t] = s; __syncthreads();
  for (int o = 1; o < 256; o <<= 1){
    int v = (t >= o) ? sd[t - o] : 0;
    __syncthreads();
    if (t >= o) sd[t] += v;
    __syncthreads();
  }
  int pre = 0;
  for (int i = 0; i < b; i++) pre += bsums[i];
  int off = pre + sd[t] - s;
  #pragma unroll
  for (int j = 0; j < 4; j++){
    int i = base + j;
    if (i < NODES){ row_ptr[i] = off; off += c[j]; }
  }
  if (b == 0 && t == 0) row_ptr[NODES] = EDGES;
}

__global__ __launch_bounds__(256) void gat_scatter(const int* __restrict__ ei, const int* __restrict__ row_ptr,
                                                    int* __restrict__ fill, int* __restrict__ col,
                                                    int* __restrict__ dstarr){
  int e = blockIdx.x * 256 + threadIdx.x;
  if (e < EDGES){
    int s = ei[e], d = ei[EDGES + e];
    int pos = row_ptr[d] + atomicAdd(&fill[d], 1);
    col[pos] = s;
    dstarr[pos] = d;
  }
}

// ---------------- fused prep: x->fp16, W transposes, ws0/wd0, zero cnt ----------------
// blocks 0..3124: cvt x; 3125..3700: Wt; 3701: ws0; 3702..3897: zero cnt

__global__ __launch_bounds__(256) void gat_prep(const float* __restrict__ x, _Float16* __restrict__ xh,
                                                const float* __restrict__ W0, const float* __restrict__ W1,
                                                const float* __restrict__ W2,
                                                _Float16* __restrict__ Wt0, _Float16* __restrict__ Wt1,
                                                _Float16* __restrict__ Wt2,
                                                const float* __restrict__ as0, const float* __restrict__ ad0,
                                                float* __restrict__ ws, float* __restrict__ wd,
                                                int* __restrict__ cnt){
  int b = blockIdx.x;
  int t = threadIdx.x;
  if (b < 3125){
    int i = b * 256 + t;
    float4 v = *(const float4*)(x + (size_t)i * 4);
    f16x4 h = { (_Float16)v.x, (_Float16)v.y, (_Float16)v.z, (_Float16)v.w };
    *(f16x4*)(xh + (size_t)i * 4) = h;
  } else if (b < 3701){
    int k = b - 3125;
    if (k < 64){
      Wt0[(size_t)t * 64 + k] = (_Float16)W0[(size_t)k * 256 + t];
    } else if (k < 320){
      int kk = k - 64;
      Wt1[(size_t)t * 256 + kk] = (_Float16)W1[(size_t)kk * 256 + t];
    } else {
      int kk = k - 320;
      if (t < 64) Wt2[(size_t)t * 256 + kk] = (_Float16)W2[(size_t)kk * 64 + t];
    }
  } else if (b == 3701){
    int h = t >> 6, c = t & 63;
    float s = 0.f, d = 0.f;
    for (int cc = 0; cc < 64; cc++){
      float w = W0[(size_t)c * 256 + h * 64 + cc];
      s += w * as0[h * 64 + cc];
      d += w * ad0[h * 64 + cc];
    }
    ws[h * 64 + c] = s;
    wd[h * 64 + c] = d;
  } else {
    int i = (b - 3702) * 256 + t;
    if (i < NODES) cnt[i] = 0;
  }
}

// ---------------- no-LDS MFMA GEMM with fused attention-coefficient epilogue ----------------
// C[M,N] = A[M,K] @ W[K,N], Wt = W^T [N][K]. No LDS, no barriers in the K loop:
// af/bf fragments are direct contiguous 16B global loads (A read once; Wt L2-hot).
// ATTN=4: N=256, wave w == head w; writes asrc/adst[row*4+w].
// ATTN=1: N=64, cross-wave LDS reduce; writes asrc/adst[row].

template<int K, int N, int ATTN>
__global__ __launch_bounds__(256) void gat_gemm_nolds(const _Float16* __restrict__ A, const _Float16* __restrict__ Wt,
                                                       _Float16* __restrict__ C,
                                                       const float* __restrict__ a_srcv, const float* __restrict__ a_dstv,
                                                       float* __restrict__ asrc, float* __restrict__ adst, int M){
  constexpr int NT = N / 64;
  int tid = threadIdx.x;
  int w = tid >> 6, l = tid & 63;
  int lg = l >> 4, lr = l & 15;
  int bm = blockIdx.x * 64;

  f32x4 acc[4][NT];
  #pragma unroll
  for (int m = 0; m < 4; m++)
    #pragma unroll
    for (int n = 0; n < NT; n++)
      acc[m][n] = (f32x4){0.f, 0.f, 0.f, 0.f};

  const _Float16* ap[4];
  bool avalid[4];
  #pragma unroll
  for (int m = 0; m < 4; m++){
    int row = bm + 16 * m + lr;
    avalid[m] = row < M;
    ap[m] = A + (size_t)(avalid[m] ? row : 0) * K + 8 * lg;
  }
  const _Float16* bp[NT];
  #pragma unroll
  for (int n = 0; n < NT; n++)
    bp[n] = Wt + (size_t)(w * (N / 4) + 16 * n + lr) * K + 8 * lg;

  f16x8 zf = {};
  for (int k0 = 0; k0 < K; k0 += 32){
    f16x8 af[4], bf[NT];
    #pragma unroll
    for (int m = 0; m < 4; m++) af[m] = avalid[m] ? *(const f16x8*)(ap[m] + k0) : zf;
    #pragma unroll
    for (int n = 0; n < NT; n++) bf[n] = *(const f16x8*)(bp[n] + k0);
    #pragma unroll
    for (int m = 0; m < 4; m++)
      #pragma unroll
      for (int n = 0; n < NT; n++)
        acc[m][n] = __builtin_amdgcn_mfma_f32_16x16x32_f16(af[m], bf[n], acc[m][n], 0, 0, 0);
  }

  #pragma unroll
  for (int m = 0; m < 4; m++){
    #pragma unroll
    for (int j = 0; j < 4; j++){
      int row = bm + 16 * m + 4 * lg + j;
      if (row < M){
        #pragma unroll
        for (int n = 0; n < NT; n++)
          C[(size_t)row * N + w * (N / 4) + 16 * n + lr] = (_Float16)acc[m][n][j];
      }
    }
  }

  if constexpr (ATTN == 4){
    float avs[4], avd[4];
    #pragma unroll
    for (int n = 0; n < 4; n++){
      avs[n] = a_srcv[w * 64 + 16 * n + lr];
      avd[n] = a_dstv[w * 64 + 16 * n + lr];
    }
    #pragma unroll
    for (int m = 0; m < 4; m++){
      #pragma unroll
      for (int j = 0; j < 4; j++){
        float s1 = acc[m][0][j] * avs[0] + acc[m][1][j] * avs[1] + acc[m][2][j] * avs[2] + acc[m][3][j] * avs[3];
        float s2 = acc[m][0][j] * avd[0] + acc[m][1][j] * avd[1] + acc[m][2][j] * avd[2] + acc[m][3][j] * avd[3];
        #pragma unroll
        for (int o = 8; o > 0; o >>= 1){ s1 += __shfl_xor(s1, o); s2 += __shfl_xor(s2, o); }
        int row = bm + 16 * m + 4 * lg + j;
        if (lr == 0 && row < M){
          asrc[row * 4 + w] = s1;
          adst[row * 4 + w] = s2;
        }
      }
    }
  }
  if constexpr (ATTN == 1){
    __shared__ float sred[2][4][64];
    float av = a_srcv[w * 16 + lr], dv = a_dstv[w * 16 + lr];
    #pragma unroll
    for (int m = 0; m < 4; m++){
      #pragma unroll
      for (int j = 0; j < 4; j++){
        float s1 = acc[m][0][j] * av;
        float s2 = acc[m][0][j] * dv;
        #pragma unroll
        for (int o = 8; o > 0; o >>= 1){ s1 += __shfl_xor(s1, o); s2 += __shfl_xor(s2, o); }
        if (lr == 0){
          sred[0][w][16 * m + 4 * lg + j] = s1;
          sred[1][w][16 * m + 4 * lg + j] = s2;
        }
      }
    }
    __syncthreads();
    if (tid < 64){
      int row = bm + tid;
      if (row < M){
        asrc[row] = sred[0][0][tid] + sred[0][1][tid] + sred[0][2][tid] + sred[0][3][tid];
        adst[row] = sred[1][0][tid] + sred[1][1][tid] + sred[1][2][tid] + sred[1][3][tid];
      }
    }
  }
}

// ---------------- block-diagonal per-head GEMM (layer 0 post-aggregate), no LDS ----------------

__global__ __launch_bounds__(256) void gat_gemm_bd(const _Float16* __restrict__ A, const _Float16* __restrict__ Bt,
                                                    const float* __restrict__ bias, _Float16* __restrict__ C, int M){
  int tid = threadIdx.x;
  int w = tid >> 6, l = tid & 63;
  int lg = l >> 4, lr = l & 15;
  int bm = blockIdx.x * 64;

  f32x4 acc[4][4];
  #pragma unroll
  for (int m = 0; m < 4; m++)
    #pragma unroll
    for (int n = 0; n < 4; n++)
      acc[m][n] = (f32x4){0.f, 0.f, 0.f, 0.f};

  f16x8 zf = {};
  #pragma unroll
  for (int ks = 0; ks < 2; ks++){
    int koff = ks * 32;
    f16x8 af[4], bf[4];
    #pragma unroll
    for (int m = 0; m < 4; m++){
      int row = bm + 16 * m + lr;
      af[m] = (row < M) ? *(const f16x8*)(A + (size_t)row * 256 + w * 64 + koff + 8 * lg) : zf;
    }
    #pragma unroll
    for (int n = 0; n < 4; n++)
      bf[n] = *(const f16x8*)(Bt + (size_t)(w * 64 + 16 * n + lr) * 64 + koff + 8 * lg);
    #pragma unroll
    for (int m = 0; m < 4; m++)
      #pragma unroll
      for (int n = 0; n < 4; n++)
        acc[m][n] = __builtin_amdgcn_mfma_f32_16x16x32_f16(af[m], bf[n], acc[m][n], 0, 0, 0);
  }

  #pragma unroll
  for (int m = 0; m < 4; m++){
    #pragma unroll
    for (int j = 0; j < 4; j++){
      int row = bm + 16 * m + 4 * lg + j;
      if (row < M){
        #pragma unroll
        for (int n = 0; n < 4; n++){
          int cc = w * 64 + 16 * n + lr;
          float o = acc[m][n][j] + bias[cc];
          o = o > 0.f ? o : expm1f(o);
          C[(size_t)row * 256 + cc] = (_Float16)o;
        }
      }
    }
  }
}

// ---------------- layer-0 attention (from x via projected vectors) ----------------

__global__ __launch_bounds__(256) void gat_attn0(const _Float16* __restrict__ xh, const float* __restrict__ ws,
                                                  const float* __restrict__ wd,
                                                  float* __restrict__ asrc, float* __restrict__ adst, int N){
  int lane = threadIdx.x & 63;
  int wid = threadIdx.x >> 6;
  int n = blockIdx.x * 4 + wid;
  if (n >= N) return;
  float v = (float)xh[(size_t)n * 64 + lane];
  #pragma unroll
  for (int h = 0; h < 4; h++){
    float s1 = v * ws[h * 64 + lane];
    float s2 = v * wd[h * 64 + lane];
    #pragma unroll
    for (int o = 32; o > 0; o >>= 1){ s1 += __shfl_xor(s1, o); s2 += __shfl_xor(s2, o); }
    if (lane == 0){ asrc[n * 4 + h] = s1; adst[n * 4 + h] = s2; }
  }
}

// ---------------- layer-0 edge exp precompute (CSR order) ----------------

__global__ __launch_bounds__(256) void gat_edge_exp0(const int* __restrict__ col, const int* __restrict__ dstarr,
                                                      const float* __restrict__ asrc, const float* __restrict__ adst,
                                                      float* __restrict__ exf){
  int i = blockIdx.x * 256 + threadIdx.x;
  if (i >= EDGES) return;
  int s = col[i], d = dstarr[i];
  float4 a = *(const float4*)&asrc[s * 4];
  float4 b = *(const float4*)&adst[d * 4];
  float4 r;
  r.x = __expf(lrelu02(a.x + b.x));
  r.y = __expf(lrelu02(a.y + b.y));
  r.z = __expf(lrelu02(a.z + b.z));
  r.w = __expf(lrelu02(a.w + b.w));
  *(float4*)&exf[(size_t)i * 4] = r;
}

// ---------------- layer-0 aggregate in 64-dim input space ----------------

__global__ __launch_bounds__(256) void gat_aggregate_in64(const _Float16* __restrict__ xh, const float* __restrict__ exf,
                                                           const float* __restrict__ asrc, const float* __restrict__ adst,
                                                           const int* __restrict__ row_ptr, const int* __restrict__ col,
                                                           _Float16* __restrict__ agg){
  int lane = threadIdx.x & 63;
  int wid = threadIdx.x >> 6;
  int d = blockIdx.x * 4 + wid;
  if (d >= NODES) return;
  int slot = lane >> 4;
  int cpos = (lane & 15) * 4;

  f32x4 acc0 = {0,0,0,0}, acc1 = {0,0,0,0}, acc2 = {0,0,0,0}, acc3 = {0,0,0,0};
  f32x4 den = {0,0,0,0};

  int e0 = row_ptr[d], e1 = row_ptr[d + 1];
  const _Float16* xb = xh + cpos;
  int e = e0;
  for (; e + 8 <= e1; e += 8){
    int eA = e + slot, eB = e + 4 + slot;
    int sA = col[eA], sB = col[eB];
    float4 fA = *(const float4*)(exf + (size_t)eA * 4);
    float4 fB = *(const float4*)(exf + (size_t)eB * 4);
    f16x4 hA = *(const f16x4*)(xb + (size_t)sA * 64);
    f16x4 hB = *(const f16x4*)(xb + (size_t)sB * 64);
    f32x4 vA = { (float)hA[0], (float)hA[1], (float)hA[2], (float)hA[3] };
    f32x4 vB = { (float)hB[0], (float)hB[1], (float)hB[2], (float)hB[3] };
    den += (f32x4){ fA.x + fB.x, fA.y + fB.y, fA.z + fB.z, fA.w + fB.w };
    acc0 += fA.x * vA + fB.x * vB;
    acc1 += fA.y * vA + fB.y * vB;
    acc2 += fA.z * vA + fB.z * vB;
    acc3 += fA.w * vA + fB.w * vB;
  }
  if (e + 4 <= e1){
    int eA = e + slot;
    int sA = col[eA];
    float4 fA = *(const float4*)(exf + (size_t)eA * 4);
    f16x4 hA = *(const f16x4*)(xb + (size_t)sA * 64);
    f32x4 vA = { (float)hA[0], (float)hA[1], (float)hA[2], (float)hA[3] };
    den += (f32x4){ fA.x, fA.y, fA.z, fA.w };
    acc0 += fA.x * vA; acc1 += fA.y * vA; acc2 += fA.z * vA; acc3 += fA.w * vA;
    e += 4;
  }
  {
    int eA = e + slot;
    if (eA < e1){
      int sA = col[eA];
      float4 fA = *(const float4*)(exf + (size_t)eA * 4);
      f16x4 hA = *(const f16x4*)(xb + (size_t)sA * 64);
      f32x4 vA = { (float)hA[0], (float)hA[1], (float)hA[2], (float)hA[3] };
      den += (f32x4){ fA.x, fA.y, fA.z, fA.w };
      acc0 += fA.x * vA; acc1 += fA.y * vA; acc2 += fA.z * vA; acc3 += fA.w * vA;
    }
  }

  #pragma unroll
  for (int off = 16; off <= 32; off <<= 1){
    acc0 += shflx4(acc0, off);
    acc1 += shflx4(acc1, off);
    acc2 += shflx4(acc2, off);
    acc3 += shflx4(acc3, off);
    den  += shflx4(den,  off);
  }

  float4 a4 = *(const float4*)&asrc[d * 4];
  float4 b4 = *(const float4*)&adst[d * 4];
  float es0 = __expf(lrelu02(a4.x + b4.x));
  float es1 = __expf(lrelu02(a4.y + b4.y));
  float es2 = __expf(lrelu02(a4.z + b4.z));
  float es3 = __expf(lrelu02(a4.w + b4.w));
  f16x4 hs = *(const f16x4*)(xh + (size_t)d * 64 + cpos);
  f32x4 vs = { (float)hs[0], (float)hs[1], (float)hs[2], (float)hs[3] };
  acc0 += es0 * vs; acc1 += es1 * vs; acc2 += es2 * vs; acc3 += es3 * vs;
  den += (f32x4){ es0, es1, es2, es3 };

  if (slot == 0){
    float i0 = 1.f / (den[0] + 1e-16f), i1 = 1.f / (den[1] + 1e-16f);
    float i2 = 1.f / (den[2] + 1e-16f), i3 = 1.f / (den[3] + 1e-16f);
    _Float16* ob = agg + (size_t)d * 256 + cpos;
    f16x4 o0 = { (_Float16)(acc0[0]*i0), (_Float16)(acc0[1]*i0), (_Float16)(acc0[2]*i0), (_Float16)(acc0[3]*i0) };
    f16x4 o1 = { (_Float16)(acc1[0]*i1), (_Float16)(acc1[1]*i1), (_Float16)(acc1[2]*i1), (_Float16)(acc1[3]*i1) };
    f16x4 o2 = { (_Float16)(acc2[0]*i2), (_Float16)(acc2[1]*i2), (_Float16)(acc2[2]*i2), (_Float16)(acc2[3]*i2) };
    f16x4 o3 = { (_Float16)(acc3[0]*i3), (_Float16)(acc3[1]*i3), (_Float16)(acc3[2]*i3), (_Float16)(acc3[3]*i3) };
    *(f16x4*)(ob)       = o0;
    *(f16x4*)(ob + 64)  = o1;
    *(f16x4*)(ob + 128) = o2;
    *(f16x4*)(ob + 192) = o3;
  }
}

// ---------------- layer-1 aggregate (4 heads, 256ch), fused exp, unroll 4 ----------------

__global__ __launch_bounds__(256) void gat_aggregate4(const _Float16* __restrict__ hH, const float* __restrict__ asrc,
                                                       const float* __restrict__ adst,
                                                       const int* __restrict__ row_ptr, const int* __restrict__ col,
                                                       const float* __restrict__ bias, _Float16* __restrict__ out){
  int lane = threadIdx.x & 63;
  int wid = threadIdx.x >> 6;
  int d = blockIdx.x * 4 + wid;
  if (d >= NODES) return;
  int q = lane >> 4;
  int co = lane * 4;

  float adq = adst[d * 4 + q];

  float ex = __expf(lrelu02(asrc[d * 4 + q] + adq));
  f16x4 hv = *(const f16x4*)(hH + (size_t)d * 256 + co);
  float4 acc = make_float4(ex * (float)hv[0], ex * (float)hv[1], ex * (float)hv[2], ex * (float)hv[3]);
  float den = ex;

  int e0 = row_ptr[d], e1 = row_ptr[d + 1];
  const _Float16* hbase = hH + co;
  int e = e0;
  for (; e + 4 <= e1; e += 4){
    int s0 = col[e], s1 = col[e + 1], s2 = col[e + 2], s3 = col[e + 3];
    float a0 = asrc[s0 * 4 + q], a1 = asrc[s1 * 4 + q], a2 = asrc[s2 * 4 + q], a3 = asrc[s3 * 4 + q];
    f16x4 h0 = *(const f16x4*)(hbase + (size_t)s0 * 256);
    f16x4 h1 = *(const f16x4*)(hbase + (size_t)s1 * 256);
    f16x4 h2 = *(const f16x4*)(hbase + (size_t)s2 * 256);
    f16x4 h3 = *(const f16x4*)(hbase + (size_t)s3 * 256);
    float x0 = __expf(lrelu02(a0 + adq));
    float x1 = __expf(lrelu02(a1 + adq));
    float x2 = __expf(lrelu02(a2 + adq));
    float x3 = __expf(lrelu02(a3 + adq));
    den += x0 + x1 + x2 + x3;
    acc.x += x0 * (float)h0[0] + x1 * (float)h1[0] + x2 * (float)h2[0] + x3 * (float)h3[0];
    acc.y += x0 * (float)h0[1] + x1 * (float)h1[1] + x2 * (float)h2[1] + x3 * (float)h3[1];
    acc.z += x0 * (float)h0[2] + x1 * (float)h1[2] + x2 * (float)h2[2] + x3 * (float)h3[2];
    acc.w += x0 * (float)h0[3] + x1 * (float)h1[3] + x2 * (float)h2[3] + x3 * (float)h3[3];
  }
  for (; e < e1; e++){
    int s0 = col[e];
    float a0 = asrc[s0 * 4 + q];
    f16x4 h0 = *(const f16x4*)(hbase + (size_t)s0 * 256);
    float x0 = __expf(lrelu02(a0 + adq));
    den += x0;
    acc.x += x0 * (float)h0[0]; acc.y += x0 * (float)h0[1];
    acc.z += x0 * (float)h0[2]; acc.w += x0 * (float)h0[3];
  }

  float inv = 1.f / (den + 1e-16f);
  float4 b4 = *(const float4*)&bias[co];
  float4 o = make_float4(acc.x * inv + b4.x, acc.y * inv + b4.y, acc.z * inv + b4.z, acc.w * inv + b4.w);
  o.x = o.x > 0.f ? o.x : expm1f(o.x);
  o.y = o.y > 0.f ? o.y : expm1f(o.y);
  o.z = o.z > 0.f ? o.z : expm1f(o.z);
  o.w = o.w > 0.f ? o.w : expm1f(o.w);
  f16x4 oh = { (_Float16)o.x, (_Float16)o.y, (_Float16)o.z, (_Float16)o.w };
  *(f16x4*)(out + (size_t)d * 256 + co) = oh;
}

// ---------------- layer-2 aggregate (1 head, 64ch): 4 edge-slots x 16 lanes, inline exp ----------------

__global__ __launch_bounds__(256) void gat_aggregate1n(const _Float16* __restrict__ hH,
                                                        const float* __restrict__ asrc, const float* __restrict__ adst,
                                                        const int* __restrict__ row_ptr, const int* __restrict__ col,
                                                        const float* __restrict__ bias, float* __restrict__ out){
  int lane = threadIdx.x & 63;
  int wid = threadIdx.x >> 6;
  int d = blockIdx.x * 4 + wid;
  if (d >= NODES) return;
  int slot = lane >> 4;
  int cpos = (lane & 15) * 4;

  float adq = adst[d];
  f32x4 acc = {0,0,0,0};
  float den = 0.f;

  int e0 = row_ptr[d], e1 = row_ptr[d + 1];
  const _Float16* hb = hH + cpos;
  int e = e0;
  for (; e + 8 <= e1; e += 8){
    int eA = e + slot, eB = e + 4 + slot;
    int sA = col[eA], sB = col[eB];
    float fA = __expf(lrelu02(asrc[sA] + adq));
    float fB = __expf(lrelu02(asrc[sB] + adq));
    f16x4 hA = *(const f16x4*)(hb + (size_t)sA * 64);
    f16x4 hB = *(const f16x4*)(hb + (size_t)sB * 64);
    f32x4 vA = { (float)hA[0], (float)hA[1], (float)hA[2], (float)hA[3] };
    f32x4 vB = { (float)hB[0], (float)hB[1], (float)hB[2], (float)hB[3] };
    den += fA + fB;
    acc += fA * vA + fB * vB;
  }
  if (e + 4 <= e1){
    int eA = e + slot;
    int sA = col[eA];
    float fA = __expf(lrelu02(asrc[sA] + adq));
    f16x4 hA = *(const f16x4*)(hb + (size_t)sA * 64);
    f32x4 vA = { (float)hA[0], (float)hA[1], (float)hA[2], (float)hA[3] };
    den += fA; acc += fA * vA;
    e += 4;
  }
  {
    int eA = e + slot;
    if (eA < e1){
      int sA = col[eA];
      float fA = __expf(lrelu02(asrc[sA] + adq));
      f16x4 hA = *(const f16x4*)(hb + (size_t)sA * 64);
      f32x4 vA = { (float)hA[0], (float)hA[1], (float)hA[2], (float)hA[3] };
      den += fA; acc += fA * vA;
    }
  }

  #pragma unroll
  for (int off = 16; off <= 32; off <<= 1){
    acc += shflx4(acc, off);
    den += __shfl_xor(den, off);
  }

  float es = __expf(lrelu02(asrc[d] + adq));
  f16x4 hs = *(const f16x4*)(hH + (size_t)d * 64 + cpos);
  f32x4 vs = { (float)hs[0], (float)hs[1], (float)hs[2], (float)hs[3] };
  acc += es * vs;
  den += es;

  if (slot == 0){
    float inv = 1.f / (den + 1e-16f);
    float4 b4 = *(const float4*)&bias[cpos];
    float4 o = make_float4(acc[0] * inv + b4.x, acc[1] * inv + b4.y, acc[2] * inv + b4.z, acc[3] * inv + b4.w);
    *(float4*)(out + (size_t)d * 64 + cpos) = o;
  }
}

// ---------------- launch ----------------

extern "C" void kernel_launch(void* const* d_in, const int* in_sizes, int n_in,
                              void* d_out, int out_size, void* d_ws, size_t ws_size,
                              hipStream_t stream) {
  const float* x   = (const float*)d_in[0];
  const int*   ei  = (const int*)  d_in[1];
  const float* W0  = (const float*)d_in[2];
  const float* as0 = (const float*)d_in[3];
  const float* ad0 = (const float*)d_in[4];
  const float* b0  = (const float*)d_in[5];
  const float* W1  = (const float*)d_in[6];
  const float* as1 = (const float*)d_in[7];
  const float* ad1 = (const float*)d_in[8];
  const float* b1  = (const float*)d_in[9];
  const float* W2  = (const float*)d_in[10];
  const float* as2 = (const float*)d_in[11];
  const float* ad2 = (const float*)d_in[12];
  const float* b2  = (const float*)d_in[13];
  float* out = (float*)d_out;

  auto al = [](size_t v){ return (v + 255) & ~(size_t)255; };
  char* p = (char*)d_ws;
  int*      row_ptr = (int*)p;      p += al((NODES + 1) * sizeof(int));
  int*      cnt     = (int*)p;      p += al(NODES * sizeof(int));
  int*      bsums   = (int*)p;      p += al(64 * sizeof(int));
  int*      col     = (int*)p;      p += al(EDGES * sizeof(int));
  int*      dstarr  = (int*)p;      p += al(EDGES * sizeof(int));
  float*    exf     = (float*)p;    p += al((size_t)EDGES * 4 * sizeof(float));
  float*    asrc    = (float*)p;    p += al(NODES * 4 * sizeof(float));
  float*    adst    = (float*)p;    p += al(NODES * 4 * sizeof(float));
  _Float16* xh      = (_Float16*)p; p += al((size_t)NODES * 64 * sizeof(_Float16));
  _Float16* hH      = (_Float16*)p; p += al((size_t)NODES * 256 * sizeof(_Float16));
  _Float16* actb    = (_Float16*)p; p += al((size_t)NODES * 256 * sizeof(_Float16));
  _Float16* Wt0     = (_Float16*)p; p += al(256 * 64 * sizeof(_Float16));
  _Float16* Wt1     = (_Float16*)p; p += al(256 * 256 * sizeof(_Float16));
  _Float16* Wt2     = (_Float16*)p; p += al(64 * 256 * sizeof(_Float16));
  float*    ws0     = (float*)p;    p += al(256 * sizeof(float));
  float*    wd0     = (float*)p;    p += al(256 * sizeof(float));

  // ---- fused prep (+ zero cnt) ----
  gat_prep<<<3898, 256, 0, stream>>>(x, xh, W0, W1, W2, Wt0, Wt1, Wt2, as0, ad0, ws0, wd0, cnt);

  // ---- CSR build (by dst) ----
  gat_hist<<<(EDGES + 255) / 256, 256, 0, stream>>>(ei, cnt);
  gat_blocksum<<<NB_SCAN, 256, 0, stream>>>(cnt, bsums);
  gat_rowptr<<<NB_SCAN, 256, 0, stream>>>(cnt, bsums, row_ptr);
  gat_scatter<<<(EDGES + 255) / 256, 256, 0, stream>>>(ei, row_ptr, cnt, col, dstarr);

  const int nodeBlocks = (NODES + 3) / 4;
  const int gemmBlocks = (NODES + 63) / 64;
  const int edgeBlocks = (EDGES + 255) / 256;

  // ---- Layer 0 (swapped): attn in input space, edge exps, aggregate x, block-diag GEMM + bias + ELU ----
  gat_attn0<<<nodeBlocks, 256, 0, stream>>>(xh, ws0, wd0, asrc, adst, NODES);
  gat_edge_exp0<<<edgeBlocks, 256, 0, stream>>>(col, dstarr, asrc, adst, exf);
  gat_aggregate_in64<<<nodeBlocks, 256, 0, stream>>>(xh, exf, asrc, adst, row_ptr, col, hH);
  gat_gemm_bd<<<gemmBlocks, 256, 0, stream>>>(hH, Wt0, b0, actb, NODES);

  // ---- Layer 1: actb @ W1 -> hH (+ fused attn); aggregate ----
  gat_gemm_nolds<256, 256, 4><<<gemmBlocks, 256, 0, stream>>>(actb, Wt1, hH, as1, ad1, asrc, adst, NODES);
  gat_aggregate4<<<nodeBlocks, 256, 0, stream>>>(hH, asrc, adst, row_ptr, col, b1, actb);

  // ---- Layer 2: actb @ W2 -> hH (64ch, + fused attn); aggregate with inline exp ----
  gat_gemm_nolds<256, 64, 1><<<gemmBlocks, 256, 0, stream>>>(actb, Wt2, hH, as2, ad2, asrc, adst, NODES);
  gat_aggregate1n<<<nodeBlocks, 256, 0, stream>>>(hH, asrc, adst, row_ptr, col, b2, out);
}

// Round 10
// 340.496 us; speedup vs baseline: 1.0724x; 1.0724x over previous
//
#include <hip/hip_runtime.h>
#include <hip/hip_fp16.h>
#include <math.h>

#define NODES 50000
#define EDGES 800000
#define NB_SCAN ((NODES + 1023) / 1024)

typedef __attribute__((ext_vector_type(8))) _Float16 f16x8;
typedef __attribute__((ext_vector_type(4))) _Float16 f16x4;
typedef __attribute__((ext_vector_type(4))) float f32x4;

__device__ __forceinline__ float lrelu02(float x){ return x > 0.f ? x : 0.2f * x; }

__device__ __forceinline__ f32x4 shflx4(f32x4 v, int m){
  f32x4 r;
  r[0] = __shfl_xor(v[0], m); r[1] = __shfl_xor(v[1], m);
  r[2] = __shfl_xor(v[2], m); r[3] = __shfl_xor(v[3], m);
  return r;
}

// ---------------- CSR build ----------------

__global__ __launch_bounds__(256) void gat_hist(const int* __restrict__ ei, int* __restrict__ cnt){
  int e = blockIdx.x * 256 + threadIdx.x;
  if (e < EDGES) atomicAdd(&cnt[ei[EDGES + e]], 1);
}

__global__ __launch_bounds__(256) void gat_blocksum(const int* __restrict__ cnt, int* __restrict__ bsums){
  __shared__ int sd[256];
  int t = threadIdx.x, b = blockIdx.x;
  int base = b * 1024 + t * 4, s = 0;
  #pragma unroll
  for (int j = 0; j < 4; j++){ int i = base + j; if (i < NODES) s += cnt[i]; }
  sd[t] = s; __syncthreads();
  for (int o = 128; o > 0; o >>= 1){ if (t < o) sd[t] += sd[t + o]; __syncthreads(); }
  if (t == 0) bsums[b] = sd[0];
}

// rowptr with inline serial scan of bsums (<=48 adds from L2 per block)
__global__ __launch_bounds__(256) void gat_rowptr(int* __restrict__ cnt, const int* __restrict__ bsums,
                                                  int* __restrict__ row_ptr){
  __shared__ int sd[256];
  int t = threadIdx.x, b = blockIdx.x;
  int base = b * 1024 + t * 4;
  int c[4]; int s = 0;
  #pragma unroll
  for (int j = 0; j < 4; j++){
    int i = base + j;
    c[j] = (i < NODES) ? cnt[i] : 0;
    s += c[j];
    if (i < NODES) cnt[i] = 0;
  }
  sd[t] = s; __syncthreads();
  for (int o = 1; o < 256; o <<= 1){
    int v = (t >= o) ? sd[t - o] : 0;
    __syncthreads();
    if (t >= o) sd[t] += v;
    __syncthreads();
  }
  int pre = 0;
  for (int i = 0; i < b; i++) pre += bsums[i];
  int off = pre + sd[t] - s;
  #pragma unroll
  for (int j = 0; j < 4; j++){
    int i = base + j;
    if (i < NODES){ row_ptr[i] = off; off += c[j]; }
  }
  if (b == 0 && t == 0) row_ptr[NODES] = EDGES;
}

__global__ __launch_bounds__(256) void gat_scatter(const int* __restrict__ ei, const int* __restrict__ row_ptr,
                                                    int* __restrict__ fill, int* __restrict__ col,
                                                    int* __restrict__ dstarr){
  int e = blockIdx.x * 256 + threadIdx.x;
  if (e < EDGES){
    int s = ei[e], d = ei[EDGES + e];
    int pos = row_ptr[d] + atomicAdd(&fill[d], 1);
    col[pos] = s;
    dstarr[pos] = d;
  }
}

// ---------------- fused prep: x->fp16, W transposes, ws0/wd0, zero cnt ----------------
// blocks 0..3124: cvt x; 3125..3700: Wt; 3701: ws0; 3702..3897: zero cnt

__global__ __launch_bounds__(256) void gat_prep(const float* __restrict__ x, _Float16* __restrict__ xh,
                                                const float* __restrict__ W0, const float* __restrict__ W1,
                                                const float* __restrict__ W2,
                                                _Float16* __restrict__ Wt0, _Float16* __restrict__ Wt1,
                                                _Float16* __restrict__ Wt2,
                                                const float* __restrict__ as0, const float* __restrict__ ad0,
                                                float* __restrict__ ws, float* __restrict__ wd,
                                                int* __restrict__ cnt){
  int b = blockIdx.x;
  int t = threadIdx.x;
  if (b < 3125){
    int i = b * 256 + t;
    float4 v = *(const float4*)(x + (size_t)i * 4);
    f16x4 h = { (_Float16)v.x, (_Float16)v.y, (_Float16)v.z, (_Float16)v.w };
    *(f16x4*)(xh + (size_t)i * 4) = h;
  } else if (b < 3701){
    int k = b - 3125;
    if (k < 64){
      Wt0[(size_t)t * 64 + k] = (_Float16)W0[(size_t)k * 256 + t];
    } else if (k < 320){
      int kk = k - 64;
      Wt1[(size_t)t * 256 + kk] = (_Float16)W1[(size_t)kk * 256 + t];
    } else {
      int kk = k - 320;
      if (t < 64) Wt2[(size_t)t * 256 + kk] = (_Float16)W2[(size_t)kk * 64 + t];
    }
  } else if (b == 3701){
    int h = t >> 6, c = t & 63;
    float s = 0.f, d = 0.f;
    for (int cc = 0; cc < 64; cc++){
      float w = W0[(size_t)c * 256 + h * 64 + cc];
      s += w * as0[h * 64 + cc];
      d += w * ad0[h * 64 + cc];
    }
    ws[h * 64 + c] = s;
    wd[h * 64 + c] = d;
  } else {
    int i = (b - 3702) * 256 + t;
    if (i < NODES) cnt[i] = 0;
  }
}

// ---------------- LDS-staged MFMA GEMM with fused attention-coefficient epilogue ----------------
// C[M,N] = A[M,K] @ W[K,N], Wt = W^T [N][K].
// ATTN=4: N=256, wave w == head w; writes asrc/adst[row*4+w].
// ATTN=1: N=64, cross-wave LDS reduce; writes asrc/adst[row].

template<int K, int N, int ATTN>
__global__ __launch_bounds__(256) void gat_gemm_mfma(const _Float16* __restrict__ A, const _Float16* __restrict__ Wt,
                                                      _Float16* __restrict__ C,
                                                      const float* __restrict__ a_srcv, const float* __restrict__ a_dstv,
                                                      float* __restrict__ asrc, float* __restrict__ adst, int M){
  constexpr int NT = N / 64;
  constexpr int LDT = 40;
  __shared__ _Float16 As[64][LDT];
  __shared__ _Float16 Bs[N][LDT];

  int tid = threadIdx.x;
  int w = tid >> 6, l = tid & 63;
  int lg = l >> 4, lr = l & 15;
  int bm = blockIdx.x * 64;

  f32x4 acc[4][NT];
  #pragma unroll
  for (int m = 0; m < 4; m++)
    #pragma unroll
    for (int n = 0; n < NT; n++)
      acc[m][n] = (f32x4){0.f, 0.f, 0.f, 0.f};

  int ar = tid >> 2;
  int akc = (tid & 3) * 8;
  bool avalid = (bm + ar) < M;
  const _Float16* aptr = A + (size_t)(bm + ar) * K + akc;

  for (int k0 = 0; k0 < K; k0 += 32){
    float4 av = avalid ? *(const float4*)(aptr + k0) : make_float4(0.f, 0.f, 0.f, 0.f);
    __syncthreads();
    *(float4*)&As[ar][akc] = av;
    #pragma unroll
    for (int c = 0; c < N / 64; c++){
      int idx = c * 256 + tid;
      int n = idx >> 2, kc = (idx & 3) * 8;
      *(float4*)&Bs[n][kc] = *(const float4*)(Wt + (size_t)n * K + k0 + kc);
    }
    __syncthreads();

    f16x8 af[4], bf[NT];
    #pragma unroll
    for (int m = 0; m < 4; m++) af[m] = *(const f16x8*)&As[16 * m + lr][8 * lg];
    #pragma unroll
    for (int n = 0; n < NT; n++) bf[n] = *(const f16x8*)&Bs[w * (N / 4) + 16 * n + lr][8 * lg];
    #pragma unroll
    for (int m = 0; m < 4; m++)
      #pragma unroll
      for (int n = 0; n < NT; n++)
        acc[m][n] = __builtin_amdgcn_mfma_f32_16x16x32_f16(af[m], bf[n], acc[m][n], 0, 0, 0);
  }

  #pragma unroll
  for (int m = 0; m < 4; m++){
    #pragma unroll
    for (int j = 0; j < 4; j++){
      int row = bm + 16 * m + 4 * lg + j;
      if (row < M){
        #pragma unroll
        for (int n = 0; n < NT; n++)
          C[(size_t)row * N + w * (N / 4) + 16 * n + lr] = (_Float16)acc[m][n][j];
      }
    }
  }

  if constexpr (ATTN == 4){
    float avs[4], avd[4];
    #pragma unroll
    for (int n = 0; n < 4; n++){
      avs[n] = a_srcv[w * 64 + 16 * n + lr];
      avd[n] = a_dstv[w * 64 + 16 * n + lr];
    }
    #pragma unroll
    for (int m = 0; m < 4; m++){
      #pragma unroll
      for (int j = 0; j < 4; j++){
        float s1 = acc[m][0][j] * avs[0] + acc[m][1][j] * avs[1] + acc[m][2][j] * avs[2] + acc[m][3][j] * avs[3];
        float s2 = acc[m][0][j] * avd[0] + acc[m][1][j] * avd[1] + acc[m][2][j] * avd[2] + acc[m][3][j] * avd[3];
        #pragma unroll
        for (int o = 8; o > 0; o >>= 1){ s1 += __shfl_xor(s1, o); s2 += __shfl_xor(s2, o); }
        int row = bm + 16 * m + 4 * lg + j;
        if (lr == 0 && row < M){
          asrc[row * 4 + w] = s1;
          adst[row * 4 + w] = s2;
        }
      }
    }
  }
  if constexpr (ATTN == 1){
    __shared__ float sred[2][4][64];
    float av = a_srcv[w * 16 + lr], dv = a_dstv[w * 16 + lr];
    #pragma unroll
    for (int m = 0; m < 4; m++){
      #pragma unroll
      for (int j = 0; j < 4; j++){
        float s1 = acc[m][0][j] * av;
        float s2 = acc[m][0][j] * dv;
        #pragma unroll
        for (int o = 8; o > 0; o >>= 1){ s1 += __shfl_xor(s1, o); s2 += __shfl_xor(s2, o); }
        if (lr == 0){
          sred[0][w][16 * m + 4 * lg + j] = s1;
          sred[1][w][16 * m + 4 * lg + j] = s2;
        }
      }
    }
    __syncthreads();
    if (tid < 64){
      int row = bm + tid;
      if (row < M){
        asrc[row] = sred[0][0][tid] + sred[0][1][tid] + sred[0][2][tid] + sred[0][3][tid];
        adst[row] = sred[1][0][tid] + sred[1][1][tid] + sred[1][2][tid] + sred[1][3][tid];
      }
    }
  }
}

// ---------------- block-diagonal per-head GEMM (layer 0 post-aggregate), no LDS ----------------

__global__ __launch_bounds__(256) void gat_gemm_bd(const _Float16* __restrict__ A, const _Float16* __restrict__ Bt,
                                                    const float* __restrict__ bias, _Float16* __restrict__ C, int M){
  int tid = threadIdx.x;
  int w = tid >> 6, l = tid & 63;
  int lg = l >> 4, lr = l & 15;
  int bm = blockIdx.x * 64;

  f32x4 acc[4][4];
  #pragma unroll
  for (int m = 0; m < 4; m++)
    #pragma unroll
    for (int n = 0; n < 4; n++)
      acc[m][n] = (f32x4){0.f, 0.f, 0.f, 0.f};

  f16x8 zf = {};
  #pragma unroll
  for (int ks = 0; ks < 2; ks++){
    int koff = ks * 32;
    f16x8 af[4], bf[4];
    #pragma unroll
    for (int m = 0; m < 4; m++){
      int row = bm + 16 * m + lr;
      af[m] = (row < M) ? *(const f16x8*)(A + (size_t)row * 256 + w * 64 + koff + 8 * lg) : zf;
    }
    #pragma unroll
    for (int n = 0; n < 4; n++)
      bf[n] = *(const f16x8*)(Bt + (size_t)(w * 64 + 16 * n + lr) * 64 + koff + 8 * lg);
    #pragma unroll
    for (int m = 0; m < 4; m++)
      #pragma unroll
      for (int n = 0; n < 4; n++)
        acc[m][n] = __builtin_amdgcn_mfma_f32_16x16x32_f16(af[m], bf[n], acc[m][n], 0, 0, 0);
  }

  #pragma unroll
  for (int m = 0; m < 4; m++){
    #pragma unroll
    for (int j = 0; j < 4; j++){
      int row = bm + 16 * m + 4 * lg + j;
      if (row < M){
        #pragma unroll
        for (int n = 0; n < 4; n++){
          int cc = w * 64 + 16 * n + lr;
          float o = acc[m][n][j] + bias[cc];
          o = o > 0.f ? o : expm1f(o);
          C[(size_t)row * 256 + cc] = (_Float16)o;
        }
      }
    }
  }
}

// ---------------- layer-0 attention (from x via projected vectors) ----------------

__global__ __launch_bounds__(256) void gat_attn0(const _Float16* __restrict__ xh, const float* __restrict__ ws,
                                                  const float* __restrict__ wd,
                                                  float* __restrict__ asrc, float* __restrict__ adst, int N){
  int lane = threadIdx.x & 63;
  int wid = threadIdx.x >> 6;
  int n = blockIdx.x * 4 + wid;
  if (n >= N) return;
  float v = (float)xh[(size_t)n * 64 + lane];
  #pragma unroll
  for (int h = 0; h < 4; h++){
    float s1 = v * ws[h * 64 + lane];
    float s2 = v * wd[h * 64 + lane];
    #pragma unroll
    for (int o = 32; o > 0; o >>= 1){ s1 += __shfl_xor(s1, o); s2 += __shfl_xor(s2, o); }
    if (lane == 0){ asrc[n * 4 + h] = s1; adst[n * 4 + h] = s2; }
  }
}

// ---------------- layer-0 edge exp precompute (CSR order) ----------------

__global__ __launch_bounds__(256) void gat_edge_exp0(const int* __restrict__ col, const int* __restrict__ dstarr,
                                                      const float* __restrict__ asrc, const float* __restrict__ adst,
                                                      float* __restrict__ exf){
  int i = blockIdx.x * 256 + threadIdx.x;
  if (i >= EDGES) return;
  int s = col[i], d = dstarr[i];
  float4 a = *(const float4*)&asrc[s * 4];
  float4 b = *(const float4*)&adst[d * 4];
  float4 r;
  r.x = __expf(lrelu02(a.x + b.x));
  r.y = __expf(lrelu02(a.y + b.y));
  r.z = __expf(lrelu02(a.z + b.z));
  r.w = __expf(lrelu02(a.w + b.w));
  *(float4*)&exf[(size_t)i * 4] = r;
}

// ---------------- layer-0 aggregate in 64-dim input space ----------------

__global__ __launch_bounds__(256) void gat_aggregate_in64(const _Float16* __restrict__ xh, const float* __restrict__ exf,
                                                           const float* __restrict__ asrc, const float* __restrict__ adst,
                                                           const int* __restrict__ row_ptr, const int* __restrict__ col,
                                                           _Float16* __restrict__ agg){
  int lane = threadIdx.x & 63;
  int wid = threadIdx.x >> 6;
  int d = blockIdx.x * 4 + wid;
  if (d >= NODES) return;
  int slot = lane >> 4;
  int cpos = (lane & 15) * 4;

  f32x4 acc0 = {0,0,0,0}, acc1 = {0,0,0,0}, acc2 = {0,0,0,0}, acc3 = {0,0,0,0};
  f32x4 den = {0,0,0,0};

  int e0 = row_ptr[d], e1 = row_ptr[d + 1];
  const _Float16* xb = xh + cpos;
  int e = e0;
  for (; e + 8 <= e1; e += 8){
    int eA = e + slot, eB = e + 4 + slot;
    int sA = col[eA], sB = col[eB];
    float4 fA = *(const float4*)(exf + (size_t)eA * 4);
    float4 fB = *(const float4*)(exf + (size_t)eB * 4);
    f16x4 hA = *(const f16x4*)(xb + (size_t)sA * 64);
    f16x4 hB = *(const f16x4*)(xb + (size_t)sB * 64);
    f32x4 vA = { (float)hA[0], (float)hA[1], (float)hA[2], (float)hA[3] };
    f32x4 vB = { (float)hB[0], (float)hB[1], (float)hB[2], (float)hB[3] };
    den += (f32x4){ fA.x + fB.x, fA.y + fB.y, fA.z + fB.z, fA.w + fB.w };
    acc0 += fA.x * vA + fB.x * vB;
    acc1 += fA.y * vA + fB.y * vB;
    acc2 += fA.z * vA + fB.z * vB;
    acc3 += fA.w * vA + fB.w * vB;
  }
  if (e + 4 <= e1){
    int eA = e + slot;
    int sA = col[eA];
    float4 fA = *(const float4*)(exf + (size_t)eA * 4);
    f16x4 hA = *(const f16x4*)(xb + (size_t)sA * 64);
    f32x4 vA = { (float)hA[0], (float)hA[1], (float)hA[2], (float)hA[3] };
    den += (f32x4){ fA.x, fA.y, fA.z, fA.w };
    acc0 += fA.x * vA; acc1 += fA.y * vA; acc2 += fA.z * vA; acc3 += fA.w * vA;
    e += 4;
  }
  {
    int eA = e + slot;
    if (eA < e1){
      int sA = col[eA];
      float4 fA = *(const float4*)(exf + (size_t)eA * 4);
      f16x4 hA = *(const f16x4*)(xb + (size_t)sA * 64);
      f32x4 vA = { (float)hA[0], (float)hA[1], (float)hA[2], (float)hA[3] };
      den += (f32x4){ fA.x, fA.y, fA.z, fA.w };
      acc0 += fA.x * vA; acc1 += fA.y * vA; acc2 += fA.z * vA; acc3 += fA.w * vA;
    }
  }

  #pragma unroll
  for (int off = 16; off <= 32; off <<= 1){
    acc0 += shflx4(acc0, off);
    acc1 += shflx4(acc1, off);
    acc2 += shflx4(acc2, off);
    acc3 += shflx4(acc3, off);
    den  += shflx4(den,  off);
  }

  float4 a4 = *(const float4*)&asrc[d * 4];
  float4 b4 = *(const float4*)&adst[d * 4];
  float es0 = __expf(lrelu02(a4.x + b4.x));
  float es1 = __expf(lrelu02(a4.y + b4.y));
  float es2 = __expf(lrelu02(a4.z + b4.z));
  float es3 = __expf(lrelu02(a4.w + b4.w));
  f16x4 hs = *(const f16x4*)(xh + (size_t)d * 64 + cpos);
  f32x4 vs = { (float)hs[0], (float)hs[1], (float)hs[2], (float)hs[3] };
  acc0 += es0 * vs; acc1 += es1 * vs; acc2 += es2 * vs; acc3 += es3 * vs;
  den += (f32x4){ es0, es1, es2, es3 };

  if (slot == 0){
    float i0 = 1.f / (den[0] + 1e-16f), i1 = 1.f / (den[1] + 1e-16f);
    float i2 = 1.f / (den[2] + 1e-16f), i3 = 1.f / (den[3] + 1e-16f);
    _Float16* ob = agg + (size_t)d * 256 + cpos;
    f16x4 o0 = { (_Float16)(acc0[0]*i0), (_Float16)(acc0[1]*i0), (_Float16)(acc0[2]*i0), (_Float16)(acc0[3]*i0) };
    f16x4 o1 = { (_Float16)(acc1[0]*i1), (_Float16)(acc1[1]*i1), (_Float16)(acc1[2]*i1), (_Float16)(acc1[3]*i1) };
    f16x4 o2 = { (_Float16)(acc2[0]*i2), (_Float16)(acc2[1]*i2), (_Float16)(acc2[2]*i2), (_Float16)(acc2[3]*i2) };
    f16x4 o3 = { (_Float16)(acc3[0]*i3), (_Float16)(acc3[1]*i3), (_Float16)(acc3[2]*i3), (_Float16)(acc3[3]*i3) };
    *(f16x4*)(ob)       = o0;
    *(f16x4*)(ob + 64)  = o1;
    *(f16x4*)(ob + 128) = o2;
    *(f16x4*)(ob + 192) = o3;
  }
}

// ---------------- layer-1 aggregate (4 heads, 256ch), fused exp, unroll 4 ----------------

__global__ __launch_bounds__(256) void gat_aggregate4(const _Float16* __restrict__ hH, const float* __restrict__ asrc,
                                                       const float* __restrict__ adst,
                                                       const int* __restrict__ row_ptr, const int* __restrict__ col,
                                                       const float* __restrict__ bias, _Float16* __restrict__ out){
  int lane = threadIdx.x & 63;
  int wid = threadIdx.x >> 6;
  int d = blockIdx.x * 4 + wid;
  if (d >= NODES) return;
  int q = lane >> 4;
  int co = lane * 4;

  float adq = adst[d * 4 + q];

  float ex = __expf(lrelu02(asrc[d * 4 + q] + adq));
  f16x4 hv = *(const f16x4*)(hH + (size_t)d * 256 + co);
  float4 acc = make_float4(ex * (float)hv[0], ex * (float)hv[1], ex * (float)hv[2], ex * (float)hv[3]);
  float den = ex;

  int e0 = row_ptr[d], e1 = row_ptr[d + 1];
  const _Float16* hbase = hH + co;
  int e = e0;
  for (; e + 4 <= e1; e += 4){
    int s0 = col[e], s1 = col[e + 1], s2 = col[e + 2], s3 = col[e + 3];
    float a0 = asrc[s0 * 4 + q], a1 = asrc[s1 * 4 + q], a2 = asrc[s2 * 4 + q], a3 = asrc[s3 * 4 + q];
    f16x4 h0 = *(const f16x4*)(hbase + (size_t)s0 * 256);
    f16x4 h1 = *(const f16x4*)(hbase + (size_t)s1 * 256);
    f16x4 h2 = *(const f16x4*)(hbase + (size_t)s2 * 256);
    f16x4 h3 = *(const f16x4*)(hbase + (size_t)s3 * 256);
    float x0 = __expf(lrelu02(a0 + adq));
    float x1 = __expf(lrelu02(a1 + adq));
    float x2 = __expf(lrelu02(a2 + adq));
    float x3 = __expf(lrelu02(a3 + adq));
    den += x0 + x1 + x2 + x3;
    acc.x += x0 * (float)h0[0] + x1 * (float)h1[0] + x2 * (float)h2[0] + x3 * (float)h3[0];
    acc.y += x0 * (float)h0[1] + x1 * (float)h1[1] + x2 * (float)h2[1] + x3 * (float)h3[1];
    acc.z += x0 * (float)h0[2] + x1 * (float)h1[2] + x2 * (float)h2[2] + x3 * (float)h3[2];
    acc.w += x0 * (float)h0[3] + x1 * (float)h1[3] + x2 * (float)h2[3] + x3 * (float)h3[3];
  }
  for (; e < e1; e++){
    int s0 = col[e];
    float a0 = asrc[s0 * 4 + q];
    f16x4 h0 = *(const f16x4*)(hbase + (size_t)s0 * 256);
    float x0 = __expf(lrelu02(a0 + adq));
    den += x0;
    acc.x += x0 * (float)h0[0]; acc.y += x0 * (float)h0[1];
    acc.z += x0 * (float)h0[2]; acc.w += x0 * (float)h0[3];
  }

  float inv = 1.f / (den + 1e-16f);
  float4 b4 = *(const float4*)&bias[co];
  float4 o = make_float4(acc.x * inv + b4.x, acc.y * inv + b4.y, acc.z * inv + b4.z, acc.w * inv + b4.w);
  o.x = o.x > 0.f ? o.x : expm1f(o.x);
  o.y = o.y > 0.f ? o.y : expm1f(o.y);
  o.z = o.z > 0.f ? o.z : expm1f(o.z);
  o.w = o.w > 0.f ? o.w : expm1f(o.w);
  f16x4 oh = { (_Float16)o.x, (_Float16)o.y, (_Float16)o.z, (_Float16)o.w };
  *(f16x4*)(out + (size_t)d * 256 + co) = oh;
}

// ---------------- layer-2 aggregate (1 head, 64ch): 4 edge-slots x 16 lanes, inline exp ----------------

__global__ __launch_bounds__(256) void gat_aggregate1n(const _Float16* __restrict__ hH,
                                                        const float* __restrict__ asrc, const float* __restrict__ adst,
                                                        const int* __restrict__ row_ptr, const int* __restrict__ col,
                                                        const float* __restrict__ bias, float* __restrict__ out){
  int lane = threadIdx.x & 63;
  int wid = threadIdx.x >> 6;
  int d = blockIdx.x * 4 + wid;
  if (d >= NODES) return;
  int slot = lane >> 4;
  int cpos = (lane & 15) * 4;

  float adq = adst[d];
  f32x4 acc = {0,0,0,0};
  float den = 0.f;

  int e0 = row_ptr[d], e1 = row_ptr[d + 1];
  const _Float16* hb = hH + cpos;
  int e = e0;
  for (; e + 8 <= e1; e += 8){
    int eA = e + slot, eB = e + 4 + slot;
    int sA = col[eA], sB = col[eB];
    float fA = __expf(lrelu02(asrc[sA] + adq));
    float fB = __expf(lrelu02(asrc[sB] + adq));
    f16x4 hA = *(const f16x4*)(hb + (size_t)sA * 64);
    f16x4 hB = *(const f16x4*)(hb + (size_t)sB * 64);
    f32x4 vA = { (float)hA[0], (float)hA[1], (float)hA[2], (float)hA[3] };
    f32x4 vB = { (float)hB[0], (float)hB[1], (float)hB[2], (float)hB[3] };
    den += fA + fB;
    acc += fA * vA + fB * vB;
  }
  if (e + 4 <= e1){
    int eA = e + slot;
    int sA = col[eA];
    float fA = __expf(lrelu02(asrc[sA] + adq));
    f16x4 hA = *(const f16x4*)(hb + (size_t)sA * 64);
    f32x4 vA = { (float)hA[0], (float)hA[1], (float)hA[2], (float)hA[3] };
    den += fA; acc += fA * vA;
    e += 4;
  }
  {
    int eA = e + slot;
    if (eA < e1){
      int sA = col[eA];
      float fA = __expf(lrelu02(asrc[sA] + adq));
      f16x4 hA = *(const f16x4*)(hb + (size_t)sA * 64);
      f32x4 vA = { (float)hA[0], (float)hA[1], (float)hA[2], (float)hA[3] };
      den += fA; acc += fA * vA;
    }
  }

  #pragma unroll
  for (int off = 16; off <= 32; off <<= 1){
    acc += shflx4(acc, off);
    den += __shfl_xor(den, off);
  }

  float es = __expf(lrelu02(asrc[d] + adq));
  f16x4 hs = *(const f16x4*)(hH + (size_t)d * 64 + cpos);
  f32x4 vs = { (float)hs[0], (float)hs[1], (float)hs[2], (float)hs[3] };
  acc += es * vs;
  den += es;

  if (slot == 0){
    float inv = 1.f / (den + 1e-16f);
    float4 b4 = *(const float4*)&bias[cpos];
    float4 o = make_float4(acc[0] * inv + b4.x, acc[1] * inv + b4.y, acc[2] * inv + b4.z, acc[3] * inv + b4.w);
    *(float4*)(out + (size_t)d * 64 + cpos) = o;
  }
}

// ---------------- launch ----------------

extern "C" void kernel_launch(void* const* d_in, const int* in_sizes, int n_in,
                              void* d_out, int out_size, void* d_ws, size_t ws_size,
                              hipStream_t stream) {
  const float* x   = (const float*)d_in[0];
  const int*   ei  = (const int*)  d_in[1];
  const float* W0  = (const float*)d_in[2];
  const float* as0 = (const float*)d_in[3];
  const float* ad0 = (const float*)d_in[4];
  const float* b0  = (const float*)d_in[5];
  const float* W1  = (const float*)d_in[6];
  const float* as1 = (const float*)d_in[7];
  const float* ad1 = (const float*)d_in[8];
  const float* b1  = (const float*)d_in[9];
  const float* W2  = (const float*)d_in[10];
  const float* as2 = (const float*)d_in[11];
  const float* ad2 = (const float*)d_in[12];
  const float* b2  = (const float*)d_in[13];
  float* out = (float*)d_out;

  auto al = [](size_t v){ return (v + 255) & ~(size_t)255; };
  char* p = (char*)d_ws;
  int*      row_ptr = (int*)p;      p += al((NODES + 1) * sizeof(int));
  int*      cnt     = (int*)p;      p += al(NODES * sizeof(int));
  int*      bsums   = (int*)p;      p += al(64 * sizeof(int));
  int*      col     = (int*)p;      p += al(EDGES * sizeof(int));
  int*      dstarr  = (int*)p;      p += al(EDGES * sizeof(int));
  float*    exf     = (float*)p;    p += al((size_t)EDGES * 4 * sizeof(float));
  float*    asrc    = (float*)p;    p += al(NODES * 4 * sizeof(float));
  float*    adst    = (float*)p;    p += al(NODES * 4 * sizeof(float));
  _Float16* xh      = (_Float16*)p; p += al((size_t)NODES * 64 * sizeof(_Float16));
  _Float16* hH      = (_Float16*)p; p += al((size_t)NODES * 256 * sizeof(_Float16));
  _Float16* actb    = (_Float16*)p; p += al((size_t)NODES * 256 * sizeof(_Float16));
  _Float16* Wt0     = (_Float16*)p; p += al(256 * 64 * sizeof(_Float16));
  _Float16* Wt1     = (_Float16*)p; p += al(256 * 256 * sizeof(_Float16));
  _Float16* Wt2     = (_Float16*)p; p += al(64 * 256 * sizeof(_Float16));
  float*    ws0     = (float*)p;    p += al(256 * sizeof(float));
  float*    wd0     = (float*)p;    p += al(256 * sizeof(float));

  // ---- fused prep (+ zero cnt) ----
  gat_prep<<<3898, 256, 0, stream>>>(x, xh, W0, W1, W2, Wt0, Wt1, Wt2, as0, ad0, ws0, wd0, cnt);

  // ---- CSR build (by dst) ----
  gat_hist<<<(EDGES + 255) / 256, 256, 0, stream>>>(ei, cnt);
  gat_blocksum<<<NB_SCAN, 256, 0, stream>>>(cnt, bsums);
  gat_rowptr<<<NB_SCAN, 256, 0, stream>>>(cnt, bsums, row_ptr);
  gat_scatter<<<(EDGES + 255) / 256, 256, 0, stream>>>(ei, row_ptr, cnt, col, dstarr);

  const int nodeBlocks = (NODES + 3) / 4;
  const int gemmBlocks = (NODES + 63) / 64;
  const int edgeBlocks = (EDGES + 255) / 256;

  // ---- Layer 0 (swapped): attn in input space, edge exps, aggregate x, block-diag GEMM + bias + ELU ----
  gat_attn0<<<nodeBlocks, 256, 0, stream>>>(xh, ws0, wd0, asrc, adst, NODES);
  gat_edge_exp0<<<edgeBlocks, 256, 0, stream>>>(col, dstarr, asrc, adst, exf);
  gat_aggregate_in64<<<nodeBlocks, 256, 0, stream>>>(xh, exf, asrc, adst, row_ptr, col, hH);
  gat_gemm_bd<<<gemmBlocks, 256, 0, stream>>>(hH, Wt0, b0, actb, NODES);

  // ---- Layer 1: actb @ W1 -> hH (+ fused attn); aggregate ----
  gat_gemm_mfma<256, 256, 4><<<gemmBlocks, 256, 0, stream>>>(actb, Wt1, hH, as1, ad1, asrc, adst, NODES);
  gat_aggregate4<<<nodeBlocks, 256, 0, stream>>>(hH, asrc, adst, row_ptr, col, b1, actb);

  // ---- Layer 2: actb @ W2 -> hH (64ch, + fused attn); aggregate with inline exp ----
  gat_gemm_mfma<256, 64, 1><<<gemmBlocks, 256, 0, stream>>>(actb, Wt2, hH, as2, ad2, asrc, adst, NODES);
  gat_aggregate1n<<<nodeBlocks, 256, 0, stream>>>(hH, asrc, adst, row_ptr, col, b2, out);
}

// Round 11
// 332.347 us; speedup vs baseline: 1.0987x; 1.0245x over previous
//
#include <hip/hip_runtime.h>
#include <hip/hip_fp16.h>
#include <math.h>

#define NODES 50000
#define EDGES 800000
#define NB_SCAN ((NODES + 1023) / 1024)

typedef __attribute__((ext_vector_type(8))) _Float16 f16x8;
typedef __attribute__((ext_vector_type(4))) _Float16 f16x4;
typedef __attribute__((ext_vector_type(4))) float f32x4;

__device__ __forceinline__ float lrelu02(float x){ return x > 0.f ? x : 0.2f * x; }

__device__ __forceinline__ f32x4 shflx4(f32x4 v, int m){
  f32x4 r;
  r[0] = __shfl_xor(v[0], m); r[1] = __shfl_xor(v[1], m);
  r[2] = __shfl_xor(v[2], m); r[3] = __shfl_xor(v[3], m);
  return r;
}

// ---------------- CSR build ----------------

__global__ __launch_bounds__(256) void gat_hist(const int* __restrict__ ei, int* __restrict__ cnt){
  int e = blockIdx.x * 256 + threadIdx.x;
  if (e < EDGES) atomicAdd(&cnt[ei[EDGES + e]], 1);
}

__global__ __launch_bounds__(256) void gat_blocksum(const int* __restrict__ cnt, int* __restrict__ bsums){
  __shared__ int sd[256];
  int t = threadIdx.x, b = blockIdx.x;
  int base = b * 1024 + t * 4, s = 0;
  #pragma unroll
  for (int j = 0; j < 4; j++){ int i = base + j; if (i < NODES) s += cnt[i]; }
  sd[t] = s; __syncthreads();
  for (int o = 128; o > 0; o >>= 1){ if (t < o) sd[t] += sd[t + o]; __syncthreads(); }
  if (t == 0) bsums[b] = sd[0];
}

// rowptr with inline serial scan of bsums (<=48 adds from L2 per block)
__global__ __launch_bounds__(256) void gat_rowptr(int* __restrict__ cnt, const int* __restrict__ bsums,
                                                  int* __restrict__ row_ptr){
  __shared__ int sd[256];
  int t = threadIdx.x, b = blockIdx.x;
  int base = b * 1024 + t * 4;
  int c[4]; int s = 0;
  #pragma unroll
  for (int j = 0; j < 4; j++){
    int i = base + j;
    c[j] = (i < NODES) ? cnt[i] : 0;
    s += c[j];
    if (i < NODES) cnt[i] = 0;
  }
  sd[t] = s; __syncthreads();
  for (int o = 1; o < 256; o <<= 1){
    int v = (t >= o) ? sd[t - o] : 0;
    __syncthreads();
    if (t >= o) sd[t] += v;
    __syncthreads();
  }
  int pre = 0;
  for (int i = 0; i < b; i++) pre += bsums[i];
  int off = pre + sd[t] - s;
  #pragma unroll
  for (int j = 0; j < 4; j++){
    int i = base + j;
    if (i < NODES){ row_ptr[i] = off; off += c[j]; }
  }
  if (b == 0 && t == 0) row_ptr[NODES] = EDGES;
}

__global__ __launch_bounds__(256) void gat_scatter(const int* __restrict__ ei, const int* __restrict__ row_ptr,
                                                    int* __restrict__ fill, int* __restrict__ col){
  int e = blockIdx.x * 256 + threadIdx.x;
  if (e < EDGES){
    int s = ei[e], d = ei[EDGES + e];
    int pos = row_ptr[d] + atomicAdd(&fill[d], 1);
    col[pos] = s;
  }
}

// ---------------- fused prep: x->fp16, W transposes, ws0/wd0, zero cnt ----------------
// blocks 0..3124: cvt x; 3125..3700: Wt; 3701: ws0; 3702..3897: zero cnt

__global__ __launch_bounds__(256) void gat_prep(const float* __restrict__ x, _Float16* __restrict__ xh,
                                                const float* __restrict__ W0, const float* __restrict__ W1,
                                                const float* __restrict__ W2,
                                                _Float16* __restrict__ Wt0, _Float16* __restrict__ Wt1,
                                                _Float16* __restrict__ Wt2,
                                                const float* __restrict__ as0, const float* __restrict__ ad0,
                                                float* __restrict__ ws, float* __restrict__ wd,
                                                int* __restrict__ cnt){
  int b = blockIdx.x;
  int t = threadIdx.x;
  if (b < 3125){
    int i = b * 256 + t;
    float4 v = *(const float4*)(x + (size_t)i * 4);
    f16x4 h = { (_Float16)v.x, (_Float16)v.y, (_Float16)v.z, (_Float16)v.w };
    *(f16x4*)(xh + (size_t)i * 4) = h;
  } else if (b < 3701){
    int k = b - 3125;
    if (k < 64){
      Wt0[(size_t)t * 64 + k] = (_Float16)W0[(size_t)k * 256 + t];
    } else if (k < 320){
      int kk = k - 64;
      Wt1[(size_t)t * 256 + kk] = (_Float16)W1[(size_t)kk * 256 + t];
    } else {
      int kk = k - 320;
      if (t < 64) Wt2[(size_t)t * 256 + kk] = (_Float16)W2[(size_t)kk * 64 + t];
    }
  } else if (b == 3701){
    int h = t >> 6, c = t & 63;
    float s = 0.f, d = 0.f;
    for (int cc = 0; cc < 64; cc++){
      float w = W0[(size_t)c * 256 + h * 64 + cc];
      s += w * as0[h * 64 + cc];
      d += w * ad0[h * 64 + cc];
    }
    ws[h * 64 + c] = s;
    wd[h * 64 + c] = d;
  } else {
    int i = (b - 3702) * 256 + t;
    if (i < NODES) cnt[i] = 0;
  }
}

// ---------------- LDS-staged MFMA GEMM (BK=64) with fused attention-coefficient epilogue ----------------
// C[M,N] = A[M,K] @ W[K,N], Wt = W^T [N][K].
// ATTN=4: N=256, wave w == head w; writes asrc/adst[row*4+w].
// ATTN=1: N=64, cross-wave LDS reduce; writes asrc/adst[row].

template<int K, int N, int ATTN>
__global__ __launch_bounds__(256) void gat_gemm_mfma(const _Float16* __restrict__ A, const _Float16* __restrict__ Wt,
                                                      _Float16* __restrict__ C,
                                                      const float* __restrict__ a_srcv, const float* __restrict__ a_dstv,
                                                      float* __restrict__ asrc, float* __restrict__ adst, int M){
  constexpr int NT = N / 64;
  constexpr int LDT = 72;     // 144B stride -> 2-way bank aliasing (free)
  __shared__ _Float16 As[64][LDT];
  __shared__ _Float16 Bs[N][LDT];

  int tid = threadIdx.x;
  int w = tid >> 6, l = tid & 63;
  int lg = l >> 4, lr = l & 15;
  int bm = blockIdx.x * 64;

  f32x4 acc[4][NT];
  #pragma unroll
  for (int m = 0; m < 4; m++)
    #pragma unroll
    for (int n = 0; n < NT; n++)
      acc[m][n] = (f32x4){0.f, 0.f, 0.f, 0.f};

  int ar = tid >> 2;
  int akc = (tid & 3) * 8;
  bool avalid = (bm + ar) < M;
  const _Float16* aptr = A + (size_t)(bm + ar) * K + akc;

  for (int k0 = 0; k0 < K; k0 += 64){
    float4 av0 = avalid ? *(const float4*)(aptr + k0)      : make_float4(0.f, 0.f, 0.f, 0.f);
    float4 av1 = avalid ? *(const float4*)(aptr + k0 + 32) : make_float4(0.f, 0.f, 0.f, 0.f);
    __syncthreads();
    *(float4*)&As[ar][akc]      = av0;
    *(float4*)&As[ar][akc + 32] = av1;
    #pragma unroll
    for (int c = 0; c < N / 32; c++){
      int idx = c * 256 + tid;
      int n = idx >> 3, kc = (idx & 7) * 8;
      *(float4*)&Bs[n][kc] = *(const float4*)(Wt + (size_t)n * K + k0 + kc);
    }
    __syncthreads();

    #pragma unroll
    for (int kk = 0; kk < 64; kk += 32){
      f16x8 af[4], bf[NT];
      #pragma unroll
      for (int m = 0; m < 4; m++) af[m] = *(const f16x8*)&As[16 * m + lr][kk + 8 * lg];
      #pragma unroll
      for (int n = 0; n < NT; n++) bf[n] = *(const f16x8*)&Bs[w * (N / 4) + 16 * n + lr][kk + 8 * lg];
      #pragma unroll
      for (int m = 0; m < 4; m++)
        #pragma unroll
        for (int n = 0; n < NT; n++)
          acc[m][n] = __builtin_amdgcn_mfma_f32_16x16x32_f16(af[m], bf[n], acc[m][n], 0, 0, 0);
    }
  }

  #pragma unroll
  for (int m = 0; m < 4; m++){
    #pragma unroll
    for (int j = 0; j < 4; j++){
      int row = bm + 16 * m + 4 * lg + j;
      if (row < M){
        #pragma unroll
        for (int n = 0; n < NT; n++)
          C[(size_t)row * N + w * (N / 4) + 16 * n + lr] = (_Float16)acc[m][n][j];
      }
    }
  }

  if constexpr (ATTN == 4){
    float avs[4], avd[4];
    #pragma unroll
    for (int n = 0; n < 4; n++){
      avs[n] = a_srcv[w * 64 + 16 * n + lr];
      avd[n] = a_dstv[w * 64 + 16 * n + lr];
    }
    #pragma unroll
    for (int m = 0; m < 4; m++){
      #pragma unroll
      for (int j = 0; j < 4; j++){
        float s1 = acc[m][0][j] * avs[0] + acc[m][1][j] * avs[1] + acc[m][2][j] * avs[2] + acc[m][3][j] * avs[3];
        float s2 = acc[m][0][j] * avd[0] + acc[m][1][j] * avd[1] + acc[m][2][j] * avd[2] + acc[m][3][j] * avd[3];
        #pragma unroll
        for (int o = 8; o > 0; o >>= 1){ s1 += __shfl_xor(s1, o); s2 += __shfl_xor(s2, o); }
        int row = bm + 16 * m + 4 * lg + j;
        if (lr == 0 && row < M){
          asrc[row * 4 + w] = s1;
          adst[row * 4 + w] = s2;
        }
      }
    }
  }
  if constexpr (ATTN == 1){
    __shared__ float sred[2][4][64];
    float av = a_srcv[w * 16 + lr], dv = a_dstv[w * 16 + lr];
    #pragma unroll
    for (int m = 0; m < 4; m++){
      #pragma unroll
      for (int j = 0; j < 4; j++){
        float s1 = acc[m][0][j] * av;
        float s2 = acc[m][0][j] * dv;
        #pragma unroll
        for (int o = 8; o > 0; o >>= 1){ s1 += __shfl_xor(s1, o); s2 += __shfl_xor(s2, o); }
        if (lr == 0){
          sred[0][w][16 * m + 4 * lg + j] = s1;
          sred[1][w][16 * m + 4 * lg + j] = s2;
        }
      }
    }
    __syncthreads();
    if (tid < 64){
      int row = bm + tid;
      if (row < M){
        asrc[row] = sred[0][0][tid] + sred[0][1][tid] + sred[0][2][tid] + sred[0][3][tid];
        adst[row] = sred[1][0][tid] + sred[1][1][tid] + sred[1][2][tid] + sred[1][3][tid];
      }
    }
  }
}

// ---------------- block-diagonal per-head GEMM (layer 0 post-aggregate), no LDS ----------------

__global__ __launch_bounds__(256) void gat_gemm_bd(const _Float16* __restrict__ A, const _Float16* __restrict__ Bt,
                                                    const float* __restrict__ bias, _Float16* __restrict__ C, int M){
  int tid = threadIdx.x;
  int w = tid >> 6, l = tid & 63;
  int lg = l >> 4, lr = l & 15;
  int bm = blockIdx.x * 64;

  f32x4 acc[4][4];
  #pragma unroll
  for (int m = 0; m < 4; m++)
    #pragma unroll
    for (int n = 0; n < 4; n++)
      acc[m][n] = (f32x4){0.f, 0.f, 0.f, 0.f};

  f16x8 zf = {};
  #pragma unroll
  for (int ks = 0; ks < 2; ks++){
    int koff = ks * 32;
    f16x8 af[4], bf[4];
    #pragma unroll
    for (int m = 0; m < 4; m++){
      int row = bm + 16 * m + lr;
      af[m] = (row < M) ? *(const f16x8*)(A + (size_t)row * 256 + w * 64 + koff + 8 * lg) : zf;
    }
    #pragma unroll
    for (int n = 0; n < 4; n++)
      bf[n] = *(const f16x8*)(Bt + (size_t)(w * 64 + 16 * n + lr) * 64 + koff + 8 * lg);
    #pragma unroll
    for (int m = 0; m < 4; m++)
      #pragma unroll
      for (int n = 0; n < 4; n++)
        acc[m][n] = __builtin_amdgcn_mfma_f32_16x16x32_f16(af[m], bf[n], acc[m][n], 0, 0, 0);
  }

  #pragma unroll
  for (int m = 0; m < 4; m++){
    #pragma unroll
    for (int j = 0; j < 4; j++){
      int row = bm + 16 * m + 4 * lg + j;
      if (row < M){
        #pragma unroll
        for (int n = 0; n < 4; n++){
          int cc = w * 64 + 16 * n + lr;
          float o = acc[m][n][j] + bias[cc];
          o = o > 0.f ? o : expm1f(o);
          C[(size_t)row * 256 + cc] = (_Float16)o;
        }
      }
    }
  }
}

// ---------------- layer-0 attention (from x via projected vectors) ----------------

__global__ __launch_bounds__(256) void gat_attn0(const _Float16* __restrict__ xh, const float* __restrict__ ws,
                                                  const float* __restrict__ wd,
                                                  float* __restrict__ asrc, float* __restrict__ adst, int N){
  int lane = threadIdx.x & 63;
  int wid = threadIdx.x >> 6;
  int n = blockIdx.x * 4 + wid;
  if (n >= N) return;
  float v = (float)xh[(size_t)n * 64 + lane];
  #pragma unroll
  for (int h = 0; h < 4; h++){
    float s1 = v * ws[h * 64 + lane];
    float s2 = v * wd[h * 64 + lane];
    #pragma unroll
    for (int o = 32; o > 0; o >>= 1){ s1 += __shfl_xor(s1, o); s2 += __shfl_xor(s2, o); }
    if (lane == 0){ asrc[n * 4 + h] = s1; adst[n * 4 + h] = s2; }
  }
}

// ---------------- layer-0 edge exp, node-parallel (16-lane group per dst; no dstarr) ----------------

__global__ __launch_bounds__(256) void gat_edge_exp0n(const float* __restrict__ asrc, const float* __restrict__ adst,
                                                       const int* __restrict__ row_ptr, const int* __restrict__ col,
                                                       float* __restrict__ exf){
  int g = (blockIdx.x * 256 + threadIdx.x) >> 4;   // dst node
  if (g >= NODES) return;
  int gl = threadIdx.x & 15;
  float4 b = *(const float4*)&adst[g * 4];
  int e0 = row_ptr[g], e1 = row_ptr[g + 1];
  for (int e = e0 + gl; e < e1; e += 16){
    int s = col[e];
    float4 a = *(const float4*)&asrc[s * 4];
    float4 r;
    r.x = __expf(lrelu02(a.x + b.x));
    r.y = __expf(lrelu02(a.y + b.y));
    r.z = __expf(lrelu02(a.z + b.z));
    r.w = __expf(lrelu02(a.w + b.w));
    *(float4*)&exf[(size_t)e * 4] = r;
  }
}

// ---------------- layer-0 aggregate in 64-dim input space ----------------

__global__ __launch_bounds__(256) void gat_aggregate_in64(const _Float16* __restrict__ xh, const float* __restrict__ exf,
                                                           const float* __restrict__ asrc, const float* __restrict__ adst,
                                                           const int* __restrict__ row_ptr, const int* __restrict__ col,
                                                           _Float16* __restrict__ agg){
  int lane = threadIdx.x & 63;
  int wid = threadIdx.x >> 6;
  int d = blockIdx.x * 4 + wid;
  if (d >= NODES) return;
  int slot = lane >> 4;
  int cpos = (lane & 15) * 4;

  f32x4 acc0 = {0,0,0,0}, acc1 = {0,0,0,0}, acc2 = {0,0,0,0}, acc3 = {0,0,0,0};
  f32x4 den = {0,0,0,0};

  int e0 = row_ptr[d], e1 = row_ptr[d + 1];
  const _Float16* xb = xh + cpos;
  int e = e0;
  for (; e + 8 <= e1; e += 8){
    int eA = e + slot, eB = e + 4 + slot;
    int sA = col[eA], sB = col[eB];
    float4 fA = *(const float4*)(exf + (size_t)eA * 4);
    float4 fB = *(const float4*)(exf + (size_t)eB * 4);
    f16x4 hA = *(const f16x4*)(xb + (size_t)sA * 64);
    f16x4 hB = *(const f16x4*)(xb + (size_t)sB * 64);
    f32x4 vA = { (float)hA[0], (float)hA[1], (float)hA[2], (float)hA[3] };
    f32x4 vB = { (float)hB[0], (float)hB[1], (float)hB[2], (float)hB[3] };
    den += (f32x4){ fA.x + fB.x, fA.y + fB.y, fA.z + fB.z, fA.w + fB.w };
    acc0 += fA.x * vA + fB.x * vB;
    acc1 += fA.y * vA + fB.y * vB;
    acc2 += fA.z * vA + fB.z * vB;
    acc3 += fA.w * vA + fB.w * vB;
  }
  if (e + 4 <= e1){
    int eA = e + slot;
    int sA = col[eA];
    float4 fA = *(const float4*)(exf + (size_t)eA * 4);
    f16x4 hA = *(const f16x4*)(xb + (size_t)sA * 64);
    f32x4 vA = { (float)hA[0], (float)hA[1], (float)hA[2], (float)hA[3] };
    den += (f32x4){ fA.x, fA.y, fA.z, fA.w };
    acc0 += fA.x * vA; acc1 += fA.y * vA; acc2 += fA.z * vA; acc3 += fA.w * vA;
    e += 4;
  }
  {
    int eA = e + slot;
    if (eA < e1){
      int sA = col[eA];
      float4 fA = *(const float4*)(exf + (size_t)eA * 4);
      f16x4 hA = *(const f16x4*)(xb + (size_t)sA * 64);
      f32x4 vA = { (float)hA[0], (float)hA[1], (float)hA[2], (float)hA[3] };
      den += (f32x4){ fA.x, fA.y, fA.z, fA.w };
      acc0 += fA.x * vA; acc1 += fA.y * vA; acc2 += fA.z * vA; acc3 += fA.w * vA;
    }
  }

  #pragma unroll
  for (int off = 16; off <= 32; off <<= 1){
    acc0 += shflx4(acc0, off);
    acc1 += shflx4(acc1, off);
    acc2 += shflx4(acc2, off);
    acc3 += shflx4(acc3, off);
    den  += shflx4(den,  off);
  }

  float4 a4 = *(const float4*)&asrc[d * 4];
  float4 b4 = *(const float4*)&adst[d * 4];
  float es0 = __expf(lrelu02(a4.x + b4.x));
  float es1 = __expf(lrelu02(a4.y + b4.y));
  float es2 = __expf(lrelu02(a4.z + b4.z));
  float es3 = __expf(lrelu02(a4.w + b4.w));
  f16x4 hs = *(const f16x4*)(xh + (size_t)d * 64 + cpos);
  f32x4 vs = { (float)hs[0], (float)hs[1], (float)hs[2], (float)hs[3] };
  acc0 += es0 * vs; acc1 += es1 * vs; acc2 += es2 * vs; acc3 += es3 * vs;
  den += (f32x4){ es0, es1, es2, es3 };

  if (slot == 0){
    float i0 = 1.f / (den[0] + 1e-16f), i1 = 1.f / (den[1] + 1e-16f);
    float i2 = 1.f / (den[2] + 1e-16f), i3 = 1.f / (den[3] + 1e-16f);
    _Float16* ob = agg + (size_t)d * 256 + cpos;
    f16x4 o0 = { (_Float16)(acc0[0]*i0), (_Float16)(acc0[1]*i0), (_Float16)(acc0[2]*i0), (_Float16)(acc0[3]*i0) };
    f16x4 o1 = { (_Float16)(acc1[0]*i1), (_Float16)(acc1[1]*i1), (_Float16)(acc1[2]*i1), (_Float16)(acc1[3]*i1) };
    f16x4 o2 = { (_Float16)(acc2[0]*i2), (_Float16)(acc2[1]*i2), (_Float16)(acc2[2]*i2), (_Float16)(acc2[3]*i2) };
    f16x4 o3 = { (_Float16)(acc3[0]*i3), (_Float16)(acc3[1]*i3), (_Float16)(acc3[2]*i3), (_Float16)(acc3[3]*i3) };
    *(f16x4*)(ob)       = o0;
    *(f16x4*)(ob + 64)  = o1;
    *(f16x4*)(ob + 128) = o2;
    *(f16x4*)(ob + 192) = o3;
  }
}

// ---------------- layer-1 aggregate (4 heads, 256ch), fused exp, unroll 4 ----------------

__global__ __launch_bounds__(256) void gat_aggregate4(const _Float16* __restrict__ hH, const float* __restrict__ asrc,
                                                       const float* __restrict__ adst,
                                                       const int* __restrict__ row_ptr, const int* __restrict__ col,
                                                       const float* __restrict__ bias, _Float16* __restrict__ out){
  int lane = threadIdx.x & 63;
  int wid = threadIdx.x >> 6;
  int d = blockIdx.x * 4 + wid;
  if (d >= NODES) return;
  int q = lane >> 4;
  int co = lane * 4;

  float adq = adst[d * 4 + q];

  float ex = __expf(lrelu02(asrc[d * 4 + q] + adq));
  f16x4 hv = *(const f16x4*)(hH + (size_t)d * 256 + co);
  float4 acc = make_float4(ex * (float)hv[0], ex * (float)hv[1], ex * (float)hv[2], ex * (float)hv[3]);
  float den = ex;

  int e0 = row_ptr[d], e1 = row_ptr[d + 1];
  const _Float16* hbase = hH + co;
  int e = e0;
  for (; e + 4 <= e1; e += 4){
    int s0 = col[e], s1 = col[e + 1], s2 = col[e + 2], s3 = col[e + 3];
    float a0 = asrc[s0 * 4 + q], a1 = asrc[s1 * 4 + q], a2 = asrc[s2 * 4 + q], a3 = asrc[s3 * 4 + q];
    f16x4 h0 = *(const f16x4*)(hbase + (size_t)s0 * 256);
    f16x4 h1 = *(const f16x4*)(hbase + (size_t)s1 * 256);
    f16x4 h2 = *(const f16x4*)(hbase + (size_t)s2 * 256);
    f16x4 h3 = *(const f16x4*)(hbase + (size_t)s3 * 256);
    float x0 = __expf(lrelu02(a0 + adq));
    float x1 = __expf(lrelu02(a1 + adq));
    float x2 = __expf(lrelu02(a2 + adq));
    float x3 = __expf(lrelu02(a3 + adq));
    den += x0 + x1 + x2 + x3;
    acc.x += x0 * (float)h0[0] + x1 * (float)h1[0] + x2 * (float)h2[0] + x3 * (float)h3[0];
    acc.y += x0 * (float)h0[1] + x1 * (float)h1[1] + x2 * (float)h2[1] + x3 * (float)h3[1];
    acc.z += x0 * (float)h0[2] + x1 * (float)h1[2] + x2 * (float)h2[2] + x3 * (float)h3[2];
    acc.w += x0 * (float)h0[3] + x1 * (float)h1[3] + x2 * (float)h2[3] + x3 * (float)h3[3];
  }
  for (; e < e1; e++){
    int s0 = col[e];
    float a0 = asrc[s0 * 4 + q];
    f16x4 h0 = *(const f16x4*)(hbase + (size_t)s0 * 256);
    float x0 = __expf(lrelu02(a0 + adq));
    den += x0;
    acc.x += x0 * (float)h0[0]; acc.y += x0 * (float)h0[1];
    acc.z += x0 * (float)h0[2]; acc.w += x0 * (float)h0[3];
  }

  float inv = 1.f / (den + 1e-16f);
  float4 b4 = *(const float4*)&bias[co];
  float4 o = make_float4(acc.x * inv + b4.x, acc.y * inv + b4.y, acc.z * inv + b4.z, acc.w * inv + b4.w);
  o.x = o.x > 0.f ? o.x : expm1f(o.x);
  o.y = o.y > 0.f ? o.y : expm1f(o.y);
  o.z = o.z > 0.f ? o.z : expm1f(o.z);
  o.w = o.w > 0.f ? o.w : expm1f(o.w);
  f16x4 oh = { (_Float16)o.x, (_Float16)o.y, (_Float16)o.z, (_Float16)o.w };
  *(f16x4*)(out + (size_t)d * 256 + co) = oh;
}

// ---------------- layer-2 aggregate (1 head, 64ch): 4 edge-slots x 16 lanes, inline exp ----------------

__global__ __launch_bounds__(256) void gat_aggregate1n(const _Float16* __restrict__ hH,
                                                        const float* __restrict__ asrc, const float* __restrict__ adst,
                                                        const int* __restrict__ row_ptr, const int* __restrict__ col,
                                                        const float* __restrict__ bias, float* __restrict__ out){
  int lane = threadIdx.x & 63;
  int wid = threadIdx.x >> 6;
  int d = blockIdx.x * 4 + wid;
  if (d >= NODES) return;
  int slot = lane >> 4;
  int cpos = (lane & 15) * 4;

  float adq = adst[d];
  f32x4 acc = {0,0,0,0};
  float den = 0.f;

  int e0 = row_ptr[d], e1 = row_ptr[d + 1];
  const _Float16* hb = hH + cpos;
  int e = e0;
  for (; e + 8 <= e1; e += 8){
    int eA = e + slot, eB = e + 4 + slot;
    int sA = col[eA], sB = col[eB];
    float fA = __expf(lrelu02(asrc[sA] + adq));
    float fB = __expf(lrelu02(asrc[sB] + adq));
    f16x4 hA = *(const f16x4*)(hb + (size_t)sA * 64);
    f16x4 hB = *(const f16x4*)(hb + (size_t)sB * 64);
    f32x4 vA = { (float)hA[0], (float)hA[1], (float)hA[2], (float)hA[3] };
    f32x4 vB = { (float)hB[0], (float)hB[1], (float)hB[2], (float)hB[3] };
    den += fA + fB;
    acc += fA * vA + fB * vB;
  }
  if (e + 4 <= e1){
    int eA = e + slot;
    int sA = col[eA];
    float fA = __expf(lrelu02(asrc[sA] + adq));
    f16x4 hA = *(const f16x4*)(hb + (size_t)sA * 64);
    f32x4 vA = { (float)hA[0], (float)hA[1], (float)hA[2], (float)hA[3] };
    den += fA; acc += fA * vA;
    e += 4;
  }
  {
    int eA = e + slot;
    if (eA < e1){
      int sA = col[eA];
      float fA = __expf(lrelu02(asrc[sA] + adq));
      f16x4 hA = *(const f16x4*)(hb + (size_t)sA * 64);
      f32x4 vA = { (float)hA[0], (float)hA[1], (float)hA[2], (float)hA[3] };
      den += fA; acc += fA * vA;
    }
  }

  #pragma unroll
  for (int off = 16; off <= 32; off <<= 1){
    acc += shflx4(acc, off);
    den += __shfl_xor(den, off);
  }

  float es = __expf(lrelu02(asrc[d] + adq));
  f16x4 hs = *(const f16x4*)(hH + (size_t)d * 64 + cpos);
  f32x4 vs = { (float)hs[0], (float)hs[1], (float)hs[2], (float)hs[3] };
  acc += es * vs;
  den += es;

  if (slot == 0){
    float inv = 1.f / (den + 1e-16f);
    float4 b4 = *(const float4*)&bias[cpos];
    float4 o = make_float4(acc[0] * inv + b4.x, acc[1] * inv + b4.y, acc[2] * inv + b4.z, acc[3] * inv + b4.w);
    *(float4*)(out + (size_t)d * 64 + cpos) = o;
  }
}

// ---------------- launch ----------------

extern "C" void kernel_launch(void* const* d_in, const int* in_sizes, int n_in,
                              void* d_out, int out_size, void* d_ws, size_t ws_size,
                              hipStream_t stream) {
  const float* x   = (const float*)d_in[0];
  const int*   ei  = (const int*)  d_in[1];
  const float* W0  = (const float*)d_in[2];
  const float* as0 = (const float*)d_in[3];
  const float* ad0 = (const float*)d_in[4];
  const float* b0  = (const float*)d_in[5];
  const float* W1  = (const float*)d_in[6];
  const float* as1 = (const float*)d_in[7];
  const float* ad1 = (const float*)d_in[8];
  const float* b1  = (const float*)d_in[9];
  const float* W2  = (const float*)d_in[10];
  const float* as2 = (const float*)d_in[11];
  const float* ad2 = (const float*)d_in[12];
  const float* b2  = (const float*)d_in[13];
  float* out = (float*)d_out;

  auto al = [](size_t v){ return (v + 255) & ~(size_t)255; };
  char* p = (char*)d_ws;
  int*      row_ptr = (int*)p;      p += al((NODES + 1) * sizeof(int));
  int*      cnt     = (int*)p;      p += al(NODES * sizeof(int));
  int*      bsums   = (int*)p;      p += al(64 * sizeof(int));
  int*      col     = (int*)p;      p += al(EDGES * sizeof(int));
  float*    exf     = (float*)p;    p += al((size_t)EDGES * 4 * sizeof(float));
  float*    asrc    = (float*)p;    p += al(NODES * 4 * sizeof(float));
  float*    adst    = (float*)p;    p += al(NODES * 4 * sizeof(float));
  _Float16* xh      = (_Float16*)p; p += al((size_t)NODES * 64 * sizeof(_Float16));
  _Float16* hH      = (_Float16*)p; p += al((size_t)NODES * 256 * sizeof(_Float16));
  _Float16* actb    = (_Float16*)p; p += al((size_t)NODES * 256 * sizeof(_Float16));
  _Float16* Wt0     = (_Float16*)p; p += al(256 * 64 * sizeof(_Float16));
  _Float16* Wt1     = (_Float16*)p; p += al(256 * 256 * sizeof(_Float16));
  _Float16* Wt2     = (_Float16*)p; p += al(64 * 256 * sizeof(_Float16));
  float*    ws0     = (float*)p;    p += al(256 * sizeof(float));
  float*    wd0     = (float*)p;    p += al(256 * sizeof(float));

  // ---- fused prep (+ zero cnt) ----
  gat_prep<<<3898, 256, 0, stream>>>(x, xh, W0, W1, W2, Wt0, Wt1, Wt2, as0, ad0, ws0, wd0, cnt);

  // ---- CSR build (by dst) ----
  gat_hist<<<(EDGES + 255) / 256, 256, 0, stream>>>(ei, cnt);
  gat_blocksum<<<NB_SCAN, 256, 0, stream>>>(cnt, bsums);
  gat_rowptr<<<NB_SCAN, 256, 0, stream>>>(cnt, bsums, row_ptr);
  gat_scatter<<<(EDGES + 255) / 256, 256, 0, stream>>>(ei, row_ptr, cnt, col);

  const int nodeBlocks = (NODES + 3) / 4;
  const int gemmBlocks = (NODES + 63) / 64;
  const int expBlocks  = (NODES * 16 + 255) / 256;

  // ---- Layer 0 (swapped): attn in input space, node-parallel edge exps, aggregate x, block-diag GEMM ----
  gat_attn0<<<nodeBlocks, 256, 0, stream>>>(xh, ws0, wd0, asrc, adst, NODES);
  gat_edge_exp0n<<<expBlocks, 256, 0, stream>>>(asrc, adst, row_ptr, col, exf);
  gat_aggregate_in64<<<nodeBlocks, 256, 0, stream>>>(xh, exf, asrc, adst, row_ptr, col, hH);
  gat_gemm_bd<<<gemmBlocks, 256, 0, stream>>>(hH, Wt0, b0, actb, NODES);

  // ---- Layer 1: actb @ W1 -> hH (+ fused attn); aggregate ----
  gat_gemm_mfma<256, 256, 4><<<gemmBlocks, 256, 0, stream>>>(actb, Wt1, hH, as1, ad1, asrc, adst, NODES);
  gat_aggregate4<<<nodeBlocks, 256, 0, stream>>>(hH, asrc, adst, row_ptr, col, b1, actb);

  // ---- Layer 2: actb @ W2 -> hH (64ch, + fused attn); aggregate with inline exp ----
  gat_gemm_mfma<256, 64, 1><<<gemmBlocks, 256, 0, stream>>>(actb, Wt2, hH, as2, ad2, asrc, adst, NODES);
  gat_aggregate1n<<<nodeBlocks, 256, 0, stream>>>(hH, asrc, adst, row_ptr, col, b2, out);
}

// Round 12
// 314.557 us; speedup vs baseline: 1.1608x; 1.0566x over previous
//
#include <hip/hip_runtime.h>
#include <hip/hip_fp16.h>
#include <math.h>

#define NODES 50000
#define EDGES 800000
#define NB_SCAN ((NODES + 1023) / 1024)

typedef __attribute__((ext_vector_type(8))) _Float16 f16x8;
typedef __attribute__((ext_vector_type(4))) _Float16 f16x4;
typedef __attribute__((ext_vector_type(4))) float f32x4;

__device__ __forceinline__ float lrelu02(float x){ return x > 0.f ? x : 0.2f * x; }

__device__ __forceinline__ f32x4 shflx4(f32x4 v, int m){
  f32x4 r;
  r[0] = __shfl_xor(v[0], m); r[1] = __shfl_xor(v[1], m);
  r[2] = __shfl_xor(v[2], m); r[3] = __shfl_xor(v[3], m);
  return r;
}

// ---------------- CSR build ----------------

__global__ __launch_bounds__(256) void gat_hist(const int* __restrict__ ei, int* __restrict__ cnt){
  int e = blockIdx.x * 256 + threadIdx.x;
  if (e < EDGES) atomicAdd(&cnt[ei[EDGES + e]], 1);
}

__global__ __launch_bounds__(256) void gat_blocksum(const int* __restrict__ cnt, int* __restrict__ bsums){
  __shared__ int sd[256];
  int t = threadIdx.x, b = blockIdx.x;
  int base = b * 1024 + t * 4, s = 0;
  #pragma unroll
  for (int j = 0; j < 4; j++){ int i = base + j; if (i < NODES) s += cnt[i]; }
  sd[t] = s; __syncthreads();
  for (int o = 128; o > 0; o >>= 1){ if (t < o) sd[t] += sd[t + o]; __syncthreads(); }
  if (t == 0) bsums[b] = sd[0];
}

// rowptr with inline serial scan of bsums (<=48 adds from L2 per block)
__global__ __launch_bounds__(256) void gat_rowptr(int* __restrict__ cnt, const int* __restrict__ bsums,
                                                  int* __restrict__ row_ptr){
  __shared__ int sd[256];
  int t = threadIdx.x, b = blockIdx.x;
  int base = b * 1024 + t * 4;
  int c[4]; int s = 0;
  #pragma unroll
  for (int j = 0; j < 4; j++){
    int i = base + j;
    c[j] = (i < NODES) ? cnt[i] : 0;
    s += c[j];
    if (i < NODES) cnt[i] = 0;
  }
  sd[t] = s; __syncthreads();
  for (int o = 1; o < 256; o <<= 1){
    int v = (t >= o) ? sd[t - o] : 0;
    __syncthreads();
    if (t >= o) sd[t] += v;
    __syncthreads();
  }
  int pre = 0;
  for (int i = 0; i < b; i++) pre += bsums[i];
  int off = pre + sd[t] - s;
  #pragma unroll
  for (int j = 0; j < 4; j++){
    int i = base + j;
    if (i < NODES){ row_ptr[i] = off; off += c[j]; }
  }
  if (b == 0 && t == 0) row_ptr[NODES] = EDGES;
}

__global__ __launch_bounds__(256) void gat_scatter(const int* __restrict__ ei, const int* __restrict__ row_ptr,
                                                    int* __restrict__ fill, int* __restrict__ col){
  int e = blockIdx.x * 256 + threadIdx.x;
  if (e < EDGES){
    int s = ei[e], d = ei[EDGES + e];
    int pos = row_ptr[d] + atomicAdd(&fill[d], 1);
    col[pos] = s;
  }
}

// ---------------- fused prep: x->fp16, W transposes, ws0/wd0, zero cnt ----------------

__global__ __launch_bounds__(256) void gat_prep(const float* __restrict__ x, _Float16* __restrict__ xh,
                                                const float* __restrict__ W0, const float* __restrict__ W1,
                                                const float* __restrict__ W2,
                                                _Float16* __restrict__ Wt0, _Float16* __restrict__ Wt1,
                                                _Float16* __restrict__ Wt2,
                                                const float* __restrict__ as0, const float* __restrict__ ad0,
                                                float* __restrict__ ws, float* __restrict__ wd,
                                                int* __restrict__ cnt){
  int b = blockIdx.x;
  int t = threadIdx.x;
  if (b < 3125){
    int i = b * 256 + t;
    float4 v = *(const float4*)(x + (size_t)i * 4);
    f16x4 h = { (_Float16)v.x, (_Float16)v.y, (_Float16)v.z, (_Float16)v.w };
    *(f16x4*)(xh + (size_t)i * 4) = h;
  } else if (b < 3701){
    int k = b - 3125;
    if (k < 64){
      Wt0[(size_t)t * 64 + k] = (_Float16)W0[(size_t)k * 256 + t];
    } else if (k < 320){
      int kk = k - 64;
      Wt1[(size_t)t * 256 + kk] = (_Float16)W1[(size_t)kk * 256 + t];
    } else {
      int kk = k - 320;
      if (t < 64) Wt2[(size_t)t * 256 + kk] = (_Float16)W2[(size_t)kk * 64 + t];
    }
  } else if (b == 3701){
    int h = t >> 6, c = t & 63;
    float s = 0.f, d = 0.f;
    for (int cc = 0; cc < 64; cc++){
      float w = W0[(size_t)c * 256 + h * 64 + cc];
      s += w * as0[h * 64 + cc];
      d += w * ad0[h * 64 + cc];
    }
    ws[h * 64 + c] = s;
    wd[h * 64 + c] = d;
  } else {
    int i = (b - 3702) * 256 + t;
    if (i < NODES) cnt[i] = 0;
  }
}

// ---------------- fused layer-0 bd-GEMM + layer-1 GEMM (+ attn4 epilogue) ----------------
// Phase 1: agg[64rows x 256] @ blockdiag(Wt0) + bias0 + ELU -> Asf (LDS, stays on chip)
// Phase 2: Asf @ W1 (Wt1 staged BK=32) -> C, + per-head attention coefficients.

__global__ __launch_bounds__(256) void gat_gemm_l0l1(const _Float16* __restrict__ agg, const _Float16* __restrict__ Bt0,
                                                      const float* __restrict__ bias0,
                                                      const _Float16* __restrict__ Wt1, _Float16* __restrict__ C,
                                                      const float* __restrict__ a_srcv, const float* __restrict__ a_dstv,
                                                      float* __restrict__ asrc, float* __restrict__ adst, int M){
  __shared__ _Float16 Asf[64][264];   // 33.8 KB; stride 264 f16 = 4 banks/row -> 2-way on b128 reads
  __shared__ _Float16 Bs[256][40];    // 20 KB

  int tid = threadIdx.x;
  int w = tid >> 6, l = tid & 63;
  int lg = l >> 4, lr = l & 15;
  int bm = blockIdx.x * 64;

  // ---- phase 1: block-diagonal per-head GEMM + bias + ELU -> Asf ----
  {
    f32x4 acc1[4][4];
    #pragma unroll
    for (int m = 0; m < 4; m++)
      #pragma unroll
      for (int n = 0; n < 4; n++)
        acc1[m][n] = (f32x4){0.f, 0.f, 0.f, 0.f};

    f16x8 zf = {};
    #pragma unroll
    for (int ks = 0; ks < 2; ks++){
      int koff = ks * 32;
      f16x8 af[4], bf[4];
      #pragma unroll
      for (int m = 0; m < 4; m++){
        int row = bm + 16 * m + lr;
        af[m] = (row < M) ? *(const f16x8*)(agg + (size_t)row * 256 + w * 64 + koff + 8 * lg) : zf;
      }
      #pragma unroll
      for (int n = 0; n < 4; n++)
        bf[n] = *(const f16x8*)(Bt0 + (size_t)(w * 64 + 16 * n + lr) * 64 + koff + 8 * lg);
      #pragma unroll
      for (int m = 0; m < 4; m++)
        #pragma unroll
        for (int n = 0; n < 4; n++)
          acc1[m][n] = __builtin_amdgcn_mfma_f32_16x16x32_f16(af[m], bf[n], acc1[m][n], 0, 0, 0);
    }

    #pragma unroll
    for (int m = 0; m < 4; m++){
      #pragma unroll
      for (int j = 0; j < 4; j++){
        int r16 = 16 * m + 4 * lg + j;
        bool valid = (bm + r16) < M;
        #pragma unroll
        for (int n = 0; n < 4; n++){
          int cc = w * 64 + 16 * n + lr;
          float o = acc1[m][n][j] + bias0[cc];
          o = o > 0.f ? o : expm1f(o);
          Asf[r16][cc] = valid ? (_Float16)o : (_Float16)0.f;
        }
      }
    }
  }

  // ---- phase 2: Asf @ W1, Bs staged per BK=32, + C write + attn4 epilogue ----
  f32x4 acc[4][4];
  #pragma unroll
  for (int m = 0; m < 4; m++)
    #pragma unroll
    for (int n = 0; n < 4; n++)
      acc[m][n] = (f32x4){0.f, 0.f, 0.f, 0.f};

  for (int k0 = 0; k0 < 256; k0 += 32){
    __syncthreads();   // k0=0: Asf writes done; k0>0: prior bf reads done
    #pragma unroll
    for (int c = 0; c < 4; c++){
      int idx = c * 256 + tid;
      int n = idx >> 2, kc = (idx & 3) * 8;
      *(float4*)&Bs[n][kc] = *(const float4*)(Wt1 + (size_t)n * 256 + k0 + kc);
    }
    __syncthreads();

    f16x8 af[4], bf[4];
    #pragma unroll
    for (int m = 0; m < 4; m++) af[m] = *(const f16x8*)&Asf[16 * m + lr][k0 + 8 * lg];
    #pragma unroll
    for (int n = 0; n < 4; n++) bf[n] = *(const f16x8*)&Bs[w * 64 + 16 * n + lr][8 * lg];
    #pragma unroll
    for (int m = 0; m < 4; m++)
      #pragma unroll
      for (int n = 0; n < 4; n++)
        acc[m][n] = __builtin_amdgcn_mfma_f32_16x16x32_f16(af[m], bf[n], acc[m][n], 0, 0, 0);
  }

  #pragma unroll
  for (int m = 0; m < 4; m++){
    #pragma unroll
    for (int j = 0; j < 4; j++){
      int row = bm + 16 * m + 4 * lg + j;
      if (row < M){
        #pragma unroll
        for (int n = 0; n < 4; n++)
          C[(size_t)row * 256 + w * 64 + 16 * n + lr] = (_Float16)acc[m][n][j];
      }
    }
  }

  // attn4 epilogue: wave w == head w
  float avs[4], avd[4];
  #pragma unroll
  for (int n = 0; n < 4; n++){
    avs[n] = a_srcv[w * 64 + 16 * n + lr];
    avd[n] = a_dstv[w * 64 + 16 * n + lr];
  }
  #pragma unroll
  for (int m = 0; m < 4; m++){
    #pragma unroll
    for (int j = 0; j < 4; j++){
      float s1 = acc[m][0][j] * avs[0] + acc[m][1][j] * avs[1] + acc[m][2][j] * avs[2] + acc[m][3][j] * avs[3];
      float s2 = acc[m][0][j] * avd[0] + acc[m][1][j] * avd[1] + acc[m][2][j] * avd[2] + acc[m][3][j] * avd[3];
      #pragma unroll
      for (int o = 8; o > 0; o >>= 1){ s1 += __shfl_xor(s1, o); s2 += __shfl_xor(s2, o); }
      int row = bm + 16 * m + 4 * lg + j;
      if (lr == 0 && row < M){
        asrc[row * 4 + w] = s1;
        adst[row * 4 + w] = s2;
      }
    }
  }
}

// ---------------- LDS-staged MFMA GEMM (BK=64) with fused ATTN=1 epilogue (layer 2) ----------------

template<int K, int N>
__global__ __launch_bounds__(256) void gat_gemm_mfma1(const _Float16* __restrict__ A, const _Float16* __restrict__ Wt,
                                                       _Float16* __restrict__ C,
                                                       const float* __restrict__ a_srcv, const float* __restrict__ a_dstv,
                                                       float* __restrict__ asrc, float* __restrict__ adst, int M){
  constexpr int NT = N / 64;
  constexpr int LDT = 72;
  __shared__ _Float16 As[64][LDT];
  __shared__ _Float16 Bs[N][LDT];

  int tid = threadIdx.x;
  int w = tid >> 6, l = tid & 63;
  int lg = l >> 4, lr = l & 15;
  int bm = blockIdx.x * 64;

  f32x4 acc[4][NT];
  #pragma unroll
  for (int m = 0; m < 4; m++)
    #pragma unroll
    for (int n = 0; n < NT; n++)
      acc[m][n] = (f32x4){0.f, 0.f, 0.f, 0.f};

  int ar = tid >> 2;
  int akc = (tid & 3) * 8;
  bool avalid = (bm + ar) < M;
  const _Float16* aptr = A + (size_t)(bm + ar) * K + akc;

  for (int k0 = 0; k0 < K; k0 += 64){
    float4 av0 = avalid ? *(const float4*)(aptr + k0)      : make_float4(0.f, 0.f, 0.f, 0.f);
    float4 av1 = avalid ? *(const float4*)(aptr + k0 + 32) : make_float4(0.f, 0.f, 0.f, 0.f);
    __syncthreads();
    *(float4*)&As[ar][akc]      = av0;
    *(float4*)&As[ar][akc + 32] = av1;
    #pragma unroll
    for (int c = 0; c < N / 32; c++){
      int idx = c * 256 + tid;
      int n = idx >> 3, kc = (idx & 7) * 8;
      *(float4*)&Bs[n][kc] = *(const float4*)(Wt + (size_t)n * K + k0 + kc);
    }
    __syncthreads();

    #pragma unroll
    for (int kk = 0; kk < 64; kk += 32){
      f16x8 af[4], bf[NT];
      #pragma unroll
      for (int m = 0; m < 4; m++) af[m] = *(const f16x8*)&As[16 * m + lr][kk + 8 * lg];
      #pragma unroll
      for (int n = 0; n < NT; n++) bf[n] = *(const f16x8*)&Bs[w * (N / 4) + 16 * n + lr][kk + 8 * lg];
      #pragma unroll
      for (int m = 0; m < 4; m++)
        #pragma unroll
        for (int n = 0; n < NT; n++)
          acc[m][n] = __builtin_amdgcn_mfma_f32_16x16x32_f16(af[m], bf[n], acc[m][n], 0, 0, 0);
    }
  }

  #pragma unroll
  for (int m = 0; m < 4; m++){
    #pragma unroll
    for (int j = 0; j < 4; j++){
      int row = bm + 16 * m + 4 * lg + j;
      if (row < M){
        #pragma unroll
        for (int n = 0; n < NT; n++)
          C[(size_t)row * N + w * (N / 4) + 16 * n + lr] = (_Float16)acc[m][n][j];
      }
    }
  }

  __shared__ float sred[2][4][64];
  float av = a_srcv[w * 16 + lr], dv = a_dstv[w * 16 + lr];
  #pragma unroll
  for (int m = 0; m < 4; m++){
    #pragma unroll
    for (int j = 0; j < 4; j++){
      float s1 = acc[m][0][j] * av;
      float s2 = acc[m][0][j] * dv;
      #pragma unroll
      for (int o = 8; o > 0; o >>= 1){ s1 += __shfl_xor(s1, o); s2 += __shfl_xor(s2, o); }
      if (lr == 0){
        sred[0][w][16 * m + 4 * lg + j] = s1;
        sred[1][w][16 * m + 4 * lg + j] = s2;
      }
    }
  }
  __syncthreads();
  if (tid < 64){
    int row = bm + tid;
    if (row < M){
      asrc[row] = sred[0][0][tid] + sred[0][1][tid] + sred[0][2][tid] + sred[0][3][tid];
      adst[row] = sred[1][0][tid] + sred[1][1][tid] + sred[1][2][tid] + sred[1][3][tid];
    }
  }
}

// ---------------- layer-0 attention (from x via projected vectors) ----------------

__global__ __launch_bounds__(256) void gat_attn0(const _Float16* __restrict__ xh, const float* __restrict__ ws,
                                                  const float* __restrict__ wd,
                                                  float* __restrict__ asrc, float* __restrict__ adst, int N){
  int lane = threadIdx.x & 63;
  int wid = threadIdx.x >> 6;
  int n = blockIdx.x * 4 + wid;
  if (n >= N) return;
  float v = (float)xh[(size_t)n * 64 + lane];
  #pragma unroll
  for (int h = 0; h < 4; h++){
    float s1 = v * ws[h * 64 + lane];
    float s2 = v * wd[h * 64 + lane];
    #pragma unroll
    for (int o = 32; o > 0; o >>= 1){ s1 += __shfl_xor(s1, o); s2 += __shfl_xor(s2, o); }
    if (lane == 0){ asrc[n * 4 + h] = s1; adst[n * 4 + h] = s2; }
  }
}

// ---------------- layer-0 edge exp, node-parallel (16-lane group per dst) ----------------

__global__ __launch_bounds__(256) void gat_edge_exp0n(const float* __restrict__ asrc, const float* __restrict__ adst,
                                                       const int* __restrict__ row_ptr, const int* __restrict__ col,
                                                       float* __restrict__ exf){
  int g = (blockIdx.x * 256 + threadIdx.x) >> 4;
  if (g >= NODES) return;
  int gl = threadIdx.x & 15;
  float4 b = *(const float4*)&adst[g * 4];
  int e0 = row_ptr[g], e1 = row_ptr[g + 1];
  for (int e = e0 + gl; e < e1; e += 16){
    int s = col[e];
    float4 a = *(const float4*)&asrc[s * 4];
    float4 r;
    r.x = __expf(lrelu02(a.x + b.x));
    r.y = __expf(lrelu02(a.y + b.y));
    r.z = __expf(lrelu02(a.z + b.z));
    r.w = __expf(lrelu02(a.w + b.w));
    *(float4*)&exf[(size_t)e * 4] = r;
  }
}

// ---------------- layer-0 aggregate in 64-dim input space ----------------

__global__ __launch_bounds__(256) void gat_aggregate_in64(const _Float16* __restrict__ xh, const float* __restrict__ exf,
                                                           const float* __restrict__ asrc, const float* __restrict__ adst,
                                                           const int* __restrict__ row_ptr, const int* __restrict__ col,
                                                           _Float16* __restrict__ agg){
  int lane = threadIdx.x & 63;
  int wid = threadIdx.x >> 6;
  int d = blockIdx.x * 4 + wid;
  if (d >= NODES) return;
  int slot = lane >> 4;
  int cpos = (lane & 15) * 4;

  f32x4 acc0 = {0,0,0,0}, acc1 = {0,0,0,0}, acc2 = {0,0,0,0}, acc3 = {0,0,0,0};
  f32x4 den = {0,0,0,0};

  int e0 = row_ptr[d], e1 = row_ptr[d + 1];
  const _Float16* xb = xh + cpos;
  int e = e0;
  for (; e + 8 <= e1; e += 8){
    int eA = e + slot, eB = e + 4 + slot;
    int sA = col[eA], sB = col[eB];
    float4 fA = *(const float4*)(exf + (size_t)eA * 4);
    float4 fB = *(const float4*)(exf + (size_t)eB * 4);
    f16x4 hA = *(const f16x4*)(xb + (size_t)sA * 64);
    f16x4 hB = *(const f16x4*)(xb + (size_t)sB * 64);
    f32x4 vA = { (float)hA[0], (float)hA[1], (float)hA[2], (float)hA[3] };
    f32x4 vB = { (float)hB[0], (float)hB[1], (float)hB[2], (float)hB[3] };
    den += (f32x4){ fA.x + fB.x, fA.y + fB.y, fA.z + fB.z, fA.w + fB.w };
    acc0 += fA.x * vA + fB.x * vB;
    acc1 += fA.y * vA + fB.y * vB;
    acc2 += fA.z * vA + fB.z * vB;
    acc3 += fA.w * vA + fB.w * vB;
  }
  if (e + 4 <= e1){
    int eA = e + slot;
    int sA = col[eA];
    float4 fA = *(const float4*)(exf + (size_t)eA * 4);
    f16x4 hA = *(const f16x4*)(xb + (size_t)sA * 64);
    f32x4 vA = { (float)hA[0], (float)hA[1], (float)hA[2], (float)hA[3] };
    den += (f32x4){ fA.x, fA.y, fA.z, fA.w };
    acc0 += fA.x * vA; acc1 += fA.y * vA; acc2 += fA.z * vA; acc3 += fA.w * vA;
    e += 4;
  }
  {
    int eA = e + slot;
    if (eA < e1){
      int sA = col[eA];
      float4 fA = *(const float4*)(exf + (size_t)eA * 4);
      f16x4 hA = *(const f16x4*)(xb + (size_t)sA * 64);
      f32x4 vA = { (float)hA[0], (float)hA[1], (float)hA[2], (float)hA[3] };
      den += (f32x4){ fA.x, fA.y, fA.z, fA.w };
      acc0 += fA.x * vA; acc1 += fA.y * vA; acc2 += fA.z * vA; acc3 += fA.w * vA;
    }
  }

  #pragma unroll
  for (int off = 16; off <= 32; off <<= 1){
    acc0 += shflx4(acc0, off);
    acc1 += shflx4(acc1, off);
    acc2 += shflx4(acc2, off);
    acc3 += shflx4(acc3, off);
    den  += shflx4(den,  off);
  }

  float4 a4 = *(const float4*)&asrc[d * 4];
  float4 b4 = *(const float4*)&adst[d * 4];
  float es0 = __expf(lrelu02(a4.x + b4.x));
  float es1 = __expf(lrelu02(a4.y + b4.y));
  float es2 = __expf(lrelu02(a4.z + b4.z));
  float es3 = __expf(lrelu02(a4.w + b4.w));
  f16x4 hs = *(const f16x4*)(xh + (size_t)d * 64 + cpos);
  f32x4 vs = { (float)hs[0], (float)hs[1], (float)hs[2], (float)hs[3] };
  acc0 += es0 * vs; acc1 += es1 * vs; acc2 += es2 * vs; acc3 += es3 * vs;
  den += (f32x4){ es0, es1, es2, es3 };

  if (slot == 0){
    float i0 = 1.f / (den[0] + 1e-16f), i1 = 1.f / (den[1] + 1e-16f);
    float i2 = 1.f / (den[2] + 1e-16f), i3 = 1.f / (den[3] + 1e-16f);
    _Float16* ob = agg + (size_t)d * 256 + cpos;
    f16x4 o0 = { (_Float16)(acc0[0]*i0), (_Float16)(acc0[1]*i0), (_Float16)(acc0[2]*i0), (_Float16)(acc0[3]*i0) };
    f16x4 o1 = { (_Float16)(acc1[0]*i1), (_Float16)(acc1[1]*i1), (_Float16)(acc1[2]*i1), (_Float16)(acc1[3]*i1) };
    f16x4 o2 = { (_Float16)(acc2[0]*i2), (_Float16)(acc2[1]*i2), (_Float16)(acc2[2]*i2), (_Float16)(acc2[3]*i2) };
    f16x4 o3 = { (_Float16)(acc3[0]*i3), (_Float16)(acc3[1]*i3), (_Float16)(acc3[2]*i3), (_Float16)(acc3[3]*i3) };
    *(f16x4*)(ob)       = o0;
    *(f16x4*)(ob + 64)  = o1;
    *(f16x4*)(ob + 128) = o2;
    *(f16x4*)(ob + 192) = o3;
  }
}

// ---------------- layer-1 aggregate (4 heads, 256ch), fused exp, unroll 4 ----------------

__global__ __launch_bounds__(256) void gat_aggregate4(const _Float16* __restrict__ hH, const float* __restrict__ asrc,
                                                       const float* __restrict__ adst,
                                                       const int* __restrict__ row_ptr, const int* __restrict__ col,
                                                       const float* __restrict__ bias, _Float16* __restrict__ out){
  int lane = threadIdx.x & 63;
  int wid = threadIdx.x >> 6;
  int d = blockIdx.x * 4 + wid;
  if (d >= NODES) return;
  int q = lane >> 4;
  int co = lane * 4;

  float adq = adst[d * 4 + q];

  float ex = __expf(lrelu02(asrc[d * 4 + q] + adq));
  f16x4 hv = *(const f16x4*)(hH + (size_t)d * 256 + co);
  float4 acc = make_float4(ex * (float)hv[0], ex * (float)hv[1], ex * (float)hv[2], ex * (float)hv[3]);
  float den = ex;

  int e0 = row_ptr[d], e1 = row_ptr[d + 1];
  const _Float16* hbase = hH + co;
  int e = e0;
  for (; e + 4 <= e1; e += 4){
    int s0 = col[e], s1 = col[e + 1], s2 = col[e + 2], s3 = col[e + 3];
    float a0 = asrc[s0 * 4 + q], a1 = asrc[s1 * 4 + q], a2 = asrc[s2 * 4 + q], a3 = asrc[s3 * 4 + q];
    f16x4 h0 = *(const f16x4*)(hbase + (size_t)s0 * 256);
    f16x4 h1 = *(const f16x4*)(hbase + (size_t)s1 * 256);
    f16x4 h2 = *(const f16x4*)(hbase + (size_t)s2 * 256);
    f16x4 h3 = *(const f16x4*)(hbase + (size_t)s3 * 256);
    float x0 = __expf(lrelu02(a0 + adq));
    float x1 = __expf(lrelu02(a1 + adq));
    float x2 = __expf(lrelu02(a2 + adq));
    float x3 = __expf(lrelu02(a3 + adq));
    den += x0 + x1 + x2 + x3;
    acc.x += x0 * (float)h0[0] + x1 * (float)h1[0] + x2 * (float)h2[0] + x3 * (float)h3[0];
    acc.y += x0 * (float)h0[1] + x1 * (float)h1[1] + x2 * (float)h2[1] + x3 * (float)h3[1];
    acc.z += x0 * (float)h0[2] + x1 * (float)h1[2] + x2 * (float)h2[2] + x3 * (float)h3[2];
    acc.w += x0 * (float)h0[3] + x1 * (float)h1[3] + x2 * (float)h2[3] + x3 * (float)h3[3];
  }
  for (; e < e1; e++){
    int s0 = col[e];
    float a0 = asrc[s0 * 4 + q];
    f16x4 h0 = *(const f16x4*)(hbase + (size_t)s0 * 256);
    float x0 = __expf(lrelu02(a0 + adq));
    den += x0;
    acc.x += x0 * (float)h0[0]; acc.y += x0 * (float)h0[1];
    acc.z += x0 * (float)h0[2]; acc.w += x0 * (float)h0[3];
  }

  float inv = 1.f / (den + 1e-16f);
  float4 b4 = *(const float4*)&bias[co];
  float4 o = make_float4(acc.x * inv + b4.x, acc.y * inv + b4.y, acc.z * inv + b4.z, acc.w * inv + b4.w);
  o.x = o.x > 0.f ? o.x : expm1f(o.x);
  o.y = o.y > 0.f ? o.y : expm1f(o.y);
  o.z = o.z > 0.f ? o.z : expm1f(o.z);
  o.w = o.w > 0.f ? o.w : expm1f(o.w);
  f16x4 oh = { (_Float16)o.x, (_Float16)o.y, (_Float16)o.z, (_Float16)o.w };
  *(f16x4*)(out + (size_t)d * 256 + co) = oh;
}

// ---------------- layer-2 aggregate (1 head, 64ch): 4 edge-slots x 16 lanes, inline exp ----------------

__global__ __launch_bounds__(256) void gat_aggregate1n(const _Float16* __restrict__ hH,
                                                        const float* __restrict__ asrc, const float* __restrict__ adst,
                                                        const int* __restrict__ row_ptr, const int* __restrict__ col,
                                                        const float* __restrict__ bias, float* __restrict__ out){
  int lane = threadIdx.x & 63;
  int wid = threadIdx.x >> 6;
  int d = blockIdx.x * 4 + wid;
  if (d >= NODES) return;
  int slot = lane >> 4;
  int cpos = (lane & 15) * 4;

  float adq = adst[d];
  f32x4 acc = {0,0,0,0};
  float den = 0.f;

  int e0 = row_ptr[d], e1 = row_ptr[d + 1];
  const _Float16* hb = hH + cpos;
  int e = e0;
  for (; e + 8 <= e1; e += 8){
    int eA = e + slot, eB = e + 4 + slot;
    int sA = col[eA], sB = col[eB];
    float fA = __expf(lrelu02(asrc[sA] + adq));
    float fB = __expf(lrelu02(asrc[sB] + adq));
    f16x4 hA = *(const f16x4*)(hb + (size_t)sA * 64);
    f16x4 hB = *(const f16x4*)(hb + (size_t)sB * 64);
    f32x4 vA = { (float)hA[0], (float)hA[1], (float)hA[2], (float)hA[3] };
    f32x4 vB = { (float)hB[0], (float)hB[1], (float)hB[2], (float)hB[3] };
    den += fA + fB;
    acc += fA * vA + fB * vB;
  }
  if (e + 4 <= e1){
    int eA = e + slot;
    int sA = col[eA];
    float fA = __expf(lrelu02(asrc[sA] + adq));
    f16x4 hA = *(const f16x4*)(hb + (size_t)sA * 64);
    f32x4 vA = { (float)hA[0], (float)hA[1], (float)hA[2], (float)hA[3] };
    den += fA; acc += fA * vA;
    e += 4;
  }
  {
    int eA = e + slot;
    if (eA < e1){
      int sA = col[eA];
      float fA = __expf(lrelu02(asrc[sA] + adq));
      f16x4 hA = *(const f16x4*)(hb + (size_t)sA * 64);
      f32x4 vA = { (float)hA[0], (float)hA[1], (float)hA[2], (float)hA[3] };
      den += fA; acc += fA * vA;
    }
  }

  #pragma unroll
  for (int off = 16; off <= 32; off <<= 1){
    acc += shflx4(acc, off);
    den += __shfl_xor(den, off);
  }

  float es = __expf(lrelu02(asrc[d] + adq));
  f16x4 hs = *(const f16x4*)(hH + (size_t)d * 64 + cpos);
  f32x4 vs = { (float)hs[0], (float)hs[1], (float)hs[2], (float)hs[3] };
  acc += es * vs;
  den += es;

  if (slot == 0){
    float inv = 1.f / (den + 1e-16f);
    float4 b4 = *(const float4*)&bias[cpos];
    float4 o = make_float4(acc[0] * inv + b4.x, acc[1] * inv + b4.y, acc[2] * inv + b4.z, acc[3] * inv + b4.w);
    *(float4*)(out + (size_t)d * 64 + cpos) = o;
  }
}

// ---------------- launch ----------------

extern "C" void kernel_launch(void* const* d_in, const int* in_sizes, int n_in,
                              void* d_out, int out_size, void* d_ws, size_t ws_size,
                              hipStream_t stream) {
  const float* x   = (const float*)d_in[0];
  const int*   ei  = (const int*)  d_in[1];
  const float* W0  = (const float*)d_in[2];
  const float* as0 = (const float*)d_in[3];
  const float* ad0 = (const float*)d_in[4];
  const float* b0  = (const float*)d_in[5];
  const float* W1  = (const float*)d_in[6];
  const float* as1 = (const float*)d_in[7];
  const float* ad1 = (const float*)d_in[8];
  const float* b1  = (const float*)d_in[9];
  const float* W2  = (const float*)d_in[10];
  const float* as2 = (const float*)d_in[11];
  const float* ad2 = (const float*)d_in[12];
  const float* b2  = (const float*)d_in[13];
  float* out = (float*)d_out;

  auto al = [](size_t v){ return (v + 255) & ~(size_t)255; };
  char* p = (char*)d_ws;
  int*      row_ptr = (int*)p;      p += al((NODES + 1) * sizeof(int));
  int*      cnt     = (int*)p;      p += al(NODES * sizeof(int));
  int*      bsums   = (int*)p;      p += al(64 * sizeof(int));
  int*      col     = (int*)p;      p += al(EDGES * sizeof(int));
  float*    exf     = (float*)p;    p += al((size_t)EDGES * 4 * sizeof(float));
  float*    asrc    = (float*)p;    p += al(NODES * 4 * sizeof(float));
  float*    adst    = (float*)p;    p += al(NODES * 4 * sizeof(float));
  _Float16* xh      = (_Float16*)p; p += al((size_t)NODES * 64 * sizeof(_Float16));
  _Float16* hH      = (_Float16*)p; p += al((size_t)NODES * 256 * sizeof(_Float16));
  _Float16* actb    = (_Float16*)p; p += al((size_t)NODES * 256 * sizeof(_Float16));
  _Float16* Wt0     = (_Float16*)p; p += al(256 * 64 * sizeof(_Float16));
  _Float16* Wt1     = (_Float16*)p; p += al(256 * 256 * sizeof(_Float16));
  _Float16* Wt2     = (_Float16*)p; p += al(64 * 256 * sizeof(_Float16));
  float*    ws0     = (float*)p;    p += al(256 * sizeof(float));
  float*    wd0     = (float*)p;    p += al(256 * sizeof(float));

  // ---- fused prep (+ zero cnt) ----
  gat_prep<<<3898, 256, 0, stream>>>(x, xh, W0, W1, W2, Wt0, Wt1, Wt2, as0, ad0, ws0, wd0, cnt);

  // ---- CSR build (by dst) ----
  gat_hist<<<(EDGES + 255) / 256, 256, 0, stream>>>(ei, cnt);
  gat_blocksum<<<NB_SCAN, 256, 0, stream>>>(cnt, bsums);
  gat_rowptr<<<NB_SCAN, 256, 0, stream>>>(cnt, bsums, row_ptr);
  gat_scatter<<<(EDGES + 255) / 256, 256, 0, stream>>>(ei, row_ptr, cnt, col);

  const int nodeBlocks = (NODES + 3) / 4;
  const int gemmBlocks = (NODES + 63) / 64;
  const int expBlocks  = (NODES * 16 + 255) / 256;

  // ---- Layer 0: attn in input space; edge exps; aggregate x (64-dim) -> hH ----
  gat_attn0<<<nodeBlocks, 256, 0, stream>>>(xh, ws0, wd0, asrc, adst, NODES);
  gat_edge_exp0n<<<expBlocks, 256, 0, stream>>>(asrc, adst, row_ptr, col, exf);
  gat_aggregate_in64<<<nodeBlocks, 256, 0, stream>>>(xh, exf, asrc, adst, row_ptr, col, hH);

  // ---- Fused: (agg @ Wt0 + b0 + ELU) @ W1 -> actb, + layer-1 attn coefficients ----
  gat_gemm_l0l1<<<gemmBlocks, 256, 0, stream>>>(hH, Wt0, b0, Wt1, actb, as1, ad1, asrc, adst, NODES);

  // ---- Layer 1 aggregate: actb -> hH ----
  gat_aggregate4<<<nodeBlocks, 256, 0, stream>>>(actb, asrc, adst, row_ptr, col, b1, hH);

  // ---- Layer 2: hH @ W2 -> actb (64ch, + attn1); aggregate -> out ----
  gat_gemm_mfma1<256, 64><<<gemmBlocks, 256, 0, stream>>>(hH, Wt2, actb, as2, ad2, asrc, adst, NODES);
  gat_aggregate1n<<<nodeBlocks, 256, 0, stream>>>(actb, asrc, adst, row_ptr, col, b2, out);
}

// Round 13
// 312.131 us; speedup vs baseline: 1.1698x; 1.0078x over previous
//
#include <hip/hip_runtime.h>
#include <hip/hip_fp16.h>
#include <math.h>

#define NODES 50000
#define EDGES 800000
#define NB_SCAN ((NODES + 1023) / 1024)

typedef __attribute__((ext_vector_type(8))) _Float16 f16x8;
typedef __attribute__((ext_vector_type(4))) _Float16 f16x4;
typedef __attribute__((ext_vector_type(4))) float f32x4;

__device__ __forceinline__ float lrelu02(float x){ return x > 0.f ? x : 0.2f * x; }

__device__ __forceinline__ f32x4 shflx4(f32x4 v, int m){
  f32x4 r;
  r[0] = __shfl_xor(v[0], m); r[1] = __shfl_xor(v[1], m);
  r[2] = __shfl_xor(v[2], m); r[3] = __shfl_xor(v[3], m);
  return r;
}

// ---------------- CSR build ----------------

__global__ __launch_bounds__(256) void gat_hist(const int* __restrict__ ei, int* __restrict__ cnt){
  int e = blockIdx.x * 256 + threadIdx.x;
  if (e < EDGES) atomicAdd(&cnt[ei[EDGES + e]], 1);
}

__global__ __launch_bounds__(256) void gat_blocksum(const int* __restrict__ cnt, int* __restrict__ bsums){
  __shared__ int sd[256];
  int t = threadIdx.x, b = blockIdx.x;
  int base = b * 1024 + t * 4, s = 0;
  #pragma unroll
  for (int j = 0; j < 4; j++){ int i = base + j; if (i < NODES) s += cnt[i]; }
  sd[t] = s; __syncthreads();
  for (int o = 128; o > 0; o >>= 1){ if (t < o) sd[t] += sd[t + o]; __syncthreads(); }
  if (t == 0) bsums[b] = sd[0];
}

// rowptr with inline serial scan of bsums (<=48 adds from L2 per block)
__global__ __launch_bounds__(256) void gat_rowptr(int* __restrict__ cnt, const int* __restrict__ bsums,
                                                  int* __restrict__ row_ptr){
  __shared__ int sd[256];
  int t = threadIdx.x, b = blockIdx.x;
  int base = b * 1024 + t * 4;
  int c[4]; int s = 0;
  #pragma unroll
  for (int j = 0; j < 4; j++){
    int i = base + j;
    c[j] = (i < NODES) ? cnt[i] : 0;
    s += c[j];
    if (i < NODES) cnt[i] = 0;
  }
  sd[t] = s; __syncthreads();
  for (int o = 1; o < 256; o <<= 1){
    int v = (t >= o) ? sd[t - o] : 0;
    __syncthreads();
    if (t >= o) sd[t] += v;
    __syncthreads();
  }
  int pre = 0;
  for (int i = 0; i < b; i++) pre += bsums[i];
  int off = pre + sd[t] - s;
  #pragma unroll
  for (int j = 0; j < 4; j++){
    int i = base + j;
    if (i < NODES){ row_ptr[i] = off; off += c[j]; }
  }
  if (b == 0 && t == 0) row_ptr[NODES] = EDGES;
}

__global__ __launch_bounds__(256) void gat_scatter(const int* __restrict__ ei, const int* __restrict__ row_ptr,
                                                    int* __restrict__ fill, int* __restrict__ col){
  int e = blockIdx.x * 256 + threadIdx.x;
  if (e < EDGES){
    int s = ei[e], d = ei[EDGES + e];
    int pos = row_ptr[d] + atomicAdd(&fill[d], 1);
    col[pos] = s;
  }
}

// ---------------- fused prep: x->fp16, W transposes, ws0/wd0, zero cnt ----------------

__global__ __launch_bounds__(256) void gat_prep(const float* __restrict__ x, _Float16* __restrict__ xh,
                                                const float* __restrict__ W0, const float* __restrict__ W1,
                                                const float* __restrict__ W2,
                                                _Float16* __restrict__ Wt0, _Float16* __restrict__ Wt1,
                                                _Float16* __restrict__ Wt2,
                                                const float* __restrict__ as0, const float* __restrict__ ad0,
                                                float* __restrict__ ws, float* __restrict__ wd,
                                                int* __restrict__ cnt){
  int b = blockIdx.x;
  int t = threadIdx.x;
  if (b < 3125){
    int i = b * 256 + t;
    float4 v = *(const float4*)(x + (size_t)i * 4);
    f16x4 h = { (_Float16)v.x, (_Float16)v.y, (_Float16)v.z, (_Float16)v.w };
    *(f16x4*)(xh + (size_t)i * 4) = h;
  } else if (b < 3701){
    int k = b - 3125;
    if (k < 64){
      Wt0[(size_t)t * 64 + k] = (_Float16)W0[(size_t)k * 256 + t];
    } else if (k < 320){
      int kk = k - 64;
      Wt1[(size_t)t * 256 + kk] = (_Float16)W1[(size_t)kk * 256 + t];
    } else {
      int kk = k - 320;
      if (t < 64) Wt2[(size_t)t * 256 + kk] = (_Float16)W2[(size_t)kk * 64 + t];
    }
  } else if (b == 3701){
    int h = t >> 6, c = t & 63;
    float s = 0.f, d = 0.f;
    for (int cc = 0; cc < 64; cc++){
      float w = W0[(size_t)c * 256 + h * 64 + cc];
      s += w * as0[h * 64 + cc];
      d += w * ad0[h * 64 + cc];
    }
    ws[h * 64 + c] = s;
    wd[h * 64 + c] = d;
  } else {
    int i = (b - 3702) * 256 + t;
    if (i < NODES) cnt[i] = 0;
  }
}

// ---------------- fused layer-0 bd-GEMM + layer-1 GEMM (+ attn4 epilogue) ----------------

__global__ __launch_bounds__(256) void gat_gemm_l0l1(const _Float16* __restrict__ agg, const _Float16* __restrict__ Bt0,
                                                      const float* __restrict__ bias0,
                                                      const _Float16* __restrict__ Wt1, _Float16* __restrict__ C,
                                                      const float* __restrict__ a_srcv, const float* __restrict__ a_dstv,
                                                      float* __restrict__ asrc, float* __restrict__ adst, int M){
  __shared__ _Float16 Asf[64][264];
  __shared__ _Float16 Bs[256][40];

  int tid = threadIdx.x;
  int w = tid >> 6, l = tid & 63;
  int lg = l >> 4, lr = l & 15;
  int bm = blockIdx.x * 64;

  // ---- phase 1: block-diagonal per-head GEMM + bias + ELU -> Asf ----
  {
    f32x4 acc1[4][4];
    #pragma unroll
    for (int m = 0; m < 4; m++)
      #pragma unroll
      for (int n = 0; n < 4; n++)
        acc1[m][n] = (f32x4){0.f, 0.f, 0.f, 0.f};

    f16x8 zf = {};
    #pragma unroll
    for (int ks = 0; ks < 2; ks++){
      int koff = ks * 32;
      f16x8 af[4], bf[4];
      #pragma unroll
      for (int m = 0; m < 4; m++){
        int row = bm + 16 * m + lr;
        af[m] = (row < M) ? *(const f16x8*)(agg + (size_t)row * 256 + w * 64 + koff + 8 * lg) : zf;
      }
      #pragma unroll
      for (int n = 0; n < 4; n++)
        bf[n] = *(const f16x8*)(Bt0 + (size_t)(w * 64 + 16 * n + lr) * 64 + koff + 8 * lg);
      #pragma unroll
      for (int m = 0; m < 4; m++)
        #pragma unroll
        for (int n = 0; n < 4; n++)
          acc1[m][n] = __builtin_amdgcn_mfma_f32_16x16x32_f16(af[m], bf[n], acc1[m][n], 0, 0, 0);
    }

    #pragma unroll
    for (int m = 0; m < 4; m++){
      #pragma unroll
      for (int j = 0; j < 4; j++){
        int r16 = 16 * m + 4 * lg + j;
        bool valid = (bm + r16) < M;
        #pragma unroll
        for (int n = 0; n < 4; n++){
          int cc = w * 64 + 16 * n + lr;
          float o = acc1[m][n][j] + bias0[cc];
          o = o > 0.f ? o : expm1f(o);
          Asf[r16][cc] = valid ? (_Float16)o : (_Float16)0.f;
        }
      }
    }
  }

  // ---- phase 2: Asf @ W1, Bs staged per BK=32, + C write + attn4 epilogue ----
  f32x4 acc[4][4];
  #pragma unroll
  for (int m = 0; m < 4; m++)
    #pragma unroll
    for (int n = 0; n < 4; n++)
      acc[m][n] = (f32x4){0.f, 0.f, 0.f, 0.f};

  for (int k0 = 0; k0 < 256; k0 += 32){
    __syncthreads();
    #pragma unroll
    for (int c = 0; c < 4; c++){
      int idx = c * 256 + tid;
      int n = idx >> 2, kc = (idx & 3) * 8;
      *(float4*)&Bs[n][kc] = *(const float4*)(Wt1 + (size_t)n * 256 + k0 + kc);
    }
    __syncthreads();

    f16x8 af[4], bf[4];
    #pragma unroll
    for (int m = 0; m < 4; m++) af[m] = *(const f16x8*)&Asf[16 * m + lr][k0 + 8 * lg];
    #pragma unroll
    for (int n = 0; n < 4; n++) bf[n] = *(const f16x8*)&Bs[w * 64 + 16 * n + lr][8 * lg];
    #pragma unroll
    for (int m = 0; m < 4; m++)
      #pragma unroll
      for (int n = 0; n < 4; n++)
        acc[m][n] = __builtin_amdgcn_mfma_f32_16x16x32_f16(af[m], bf[n], acc[m][n], 0, 0, 0);
  }

  #pragma unroll
  for (int m = 0; m < 4; m++){
    #pragma unroll
    for (int j = 0; j < 4; j++){
      int row = bm + 16 * m + 4 * lg + j;
      if (row < M){
        #pragma unroll
        for (int n = 0; n < 4; n++)
          C[(size_t)row * 256 + w * 64 + 16 * n + lr] = (_Float16)acc[m][n][j];
      }
    }
  }

  float avs[4], avd[4];
  #pragma unroll
  for (int n = 0; n < 4; n++){
    avs[n] = a_srcv[w * 64 + 16 * n + lr];
    avd[n] = a_dstv[w * 64 + 16 * n + lr];
  }
  #pragma unroll
  for (int m = 0; m < 4; m++){
    #pragma unroll
    for (int j = 0; j < 4; j++){
      float s1 = acc[m][0][j] * avs[0] + acc[m][1][j] * avs[1] + acc[m][2][j] * avs[2] + acc[m][3][j] * avs[3];
      float s2 = acc[m][0][j] * avd[0] + acc[m][1][j] * avd[1] + acc[m][2][j] * avd[2] + acc[m][3][j] * avd[3];
      #pragma unroll
      for (int o = 8; o > 0; o >>= 1){ s1 += __shfl_xor(s1, o); s2 += __shfl_xor(s2, o); }
      int row = bm + 16 * m + 4 * lg + j;
      if (lr == 0 && row < M){
        asrc[row * 4 + w] = s1;
        adst[row * 4 + w] = s2;
      }
    }
  }
}

// ---------------- LDS-staged MFMA GEMM (BK=64) with fused ATTN=1 epilogue (layer 2) ----------------

template<int K, int N>
__global__ __launch_bounds__(256) void gat_gemm_mfma1(const _Float16* __restrict__ A, const _Float16* __restrict__ Wt,
                                                       _Float16* __restrict__ C,
                                                       const float* __restrict__ a_srcv, const float* __restrict__ a_dstv,
                                                       float* __restrict__ asrc, float* __restrict__ adst, int M){
  constexpr int NT = N / 64;
  constexpr int LDT = 72;
  __shared__ _Float16 As[64][LDT];
  __shared__ _Float16 Bs[N][LDT];

  int tid = threadIdx.x;
  int w = tid >> 6, l = tid & 63;
  int lg = l >> 4, lr = l & 15;
  int bm = blockIdx.x * 64;

  f32x4 acc[4][NT];
  #pragma unroll
  for (int m = 0; m < 4; m++)
    #pragma unroll
    for (int n = 0; n < NT; n++)
      acc[m][n] = (f32x4){0.f, 0.f, 0.f, 0.f};

  int ar = tid >> 2;
  int akc = (tid & 3) * 8;
  bool avalid = (bm + ar) < M;
  const _Float16* aptr = A + (size_t)(bm + ar) * K + akc;

  for (int k0 = 0; k0 < K; k0 += 64){
    float4 av0 = avalid ? *(const float4*)(aptr + k0)      : make_float4(0.f, 0.f, 0.f, 0.f);
    float4 av1 = avalid ? *(const float4*)(aptr + k0 + 32) : make_float4(0.f, 0.f, 0.f, 0.f);
    __syncthreads();
    *(float4*)&As[ar][akc]      = av0;
    *(float4*)&As[ar][akc + 32] = av1;
    #pragma unroll
    for (int c = 0; c < N / 32; c++){
      int idx = c * 256 + tid;
      int n = idx >> 3, kc = (idx & 7) * 8;
      *(float4*)&Bs[n][kc] = *(const float4*)(Wt + (size_t)n * K + k0 + kc);
    }
    __syncthreads();

    #pragma unroll
    for (int kk = 0; kk < 64; kk += 32){
      f16x8 af[4], bf[NT];
      #pragma unroll
      for (int m = 0; m < 4; m++) af[m] = *(const f16x8*)&As[16 * m + lr][kk + 8 * lg];
      #pragma unroll
      for (int n = 0; n < NT; n++) bf[n] = *(const f16x8*)&Bs[w * (N / 4) + 16 * n + lr][kk + 8 * lg];
      #pragma unroll
      for (int m = 0; m < 4; m++)
        #pragma unroll
        for (int n = 0; n < NT; n++)
          acc[m][n] = __builtin_amdgcn_mfma_f32_16x16x32_f16(af[m], bf[n], acc[m][n], 0, 0, 0);
    }
  }

  #pragma unroll
  for (int m = 0; m < 4; m++){
    #pragma unroll
    for (int j = 0; j < 4; j++){
      int row = bm + 16 * m + 4 * lg + j;
      if (row < M){
        #pragma unroll
        for (int n = 0; n < NT; n++)
          C[(size_t)row * N + w * (N / 4) + 16 * n + lr] = (_Float16)acc[m][n][j];
      }
    }
  }

  __shared__ float sred[2][4][64];
  float av = a_srcv[w * 16 + lr], dv = a_dstv[w * 16 + lr];
  #pragma unroll
  for (int m = 0; m < 4; m++){
    #pragma unroll
    for (int j = 0; j < 4; j++){
      float s1 = acc[m][0][j] * av;
      float s2 = acc[m][0][j] * dv;
      #pragma unroll
      for (int o = 8; o > 0; o >>= 1){ s1 += __shfl_xor(s1, o); s2 += __shfl_xor(s2, o); }
      if (lr == 0){
        sred[0][w][16 * m + 4 * lg + j] = s1;
        sred[1][w][16 * m + 4 * lg + j] = s2;
      }
    }
  }
  __syncthreads();
  if (tid < 64){
    int row = bm + tid;
    if (row < M){
      asrc[row] = sred[0][0][tid] + sred[0][1][tid] + sred[0][2][tid] + sred[0][3][tid];
      adst[row] = sred[1][0][tid] + sred[1][1][tid] + sred[1][2][tid] + sred[1][3][tid];
    }
  }
}

// ---------------- layer-0 attention (from x via projected vectors) ----------------

__global__ __launch_bounds__(256) void gat_attn0(const _Float16* __restrict__ xh, const float* __restrict__ ws,
                                                  const float* __restrict__ wd,
                                                  float* __restrict__ asrc, float* __restrict__ adst, int N){
  int lane = threadIdx.x & 63;
  int wid = threadIdx.x >> 6;
  int n = blockIdx.x * 4 + wid;
  if (n >= N) return;
  float v = (float)xh[(size_t)n * 64 + lane];
  #pragma unroll
  for (int h = 0; h < 4; h++){
    float s1 = v * ws[h * 64 + lane];
    float s2 = v * wd[h * 64 + lane];
    #pragma unroll
    for (int o = 32; o > 0; o >>= 1){ s1 += __shfl_xor(s1, o); s2 += __shfl_xor(s2, o); }
    if (lane == 0){ asrc[n * 4 + h] = s1; adst[n * 4 + h] = s2; }
  }
}

// ---------------- layer-0 aggregate in 64-dim input space, slot-amortized inline exp ----------------
// wave = 4 edge-slots x 16 lanes; one exp-instruction covers all 4 slots (lane redundancy
// within a slot is free: VALU cost is per-wave-instruction, not per-active-lane).

__global__ __launch_bounds__(256) void gat_aggregate_in64(const _Float16* __restrict__ xh,
                                                           const float* __restrict__ asrc, const float* __restrict__ adst,
                                                           const int* __restrict__ row_ptr, const int* __restrict__ col,
                                                           _Float16* __restrict__ agg){
  int lane = threadIdx.x & 63;
  int wid = threadIdx.x >> 6;
  int d = blockIdx.x * 4 + wid;
  if (d >= NODES) return;
  int slot = lane >> 4;
  int cpos = (lane & 15) * 4;

  float4 ad4 = *(const float4*)&adst[d * 4];

  f32x4 acc0 = {0,0,0,0}, acc1 = {0,0,0,0}, acc2 = {0,0,0,0}, acc3 = {0,0,0,0};
  f32x4 den = {0,0,0,0};

  int e0 = row_ptr[d], e1 = row_ptr[d + 1];
  const _Float16* xb = xh + cpos;
  int e = e0;
  for (; e + 8 <= e1; e += 8){
    int eA = e + slot, eB = e + 4 + slot;
    int sA = col[eA], sB = col[eB];
    float4 aA = *(const float4*)&asrc[sA * 4];
    float4 aB = *(const float4*)&asrc[sB * 4];
    f16x4 hA = *(const f16x4*)(xb + (size_t)sA * 64);
    f16x4 hB = *(const f16x4*)(xb + (size_t)sB * 64);
    float4 fA, fB;
    fA.x = __expf(lrelu02(aA.x + ad4.x)); fA.y = __expf(lrelu02(aA.y + ad4.y));
    fA.z = __expf(lrelu02(aA.z + ad4.z)); fA.w = __expf(lrelu02(aA.w + ad4.w));
    fB.x = __expf(lrelu02(aB.x + ad4.x)); fB.y = __expf(lrelu02(aB.y + ad4.y));
    fB.z = __expf(lrelu02(aB.z + ad4.z)); fB.w = __expf(lrelu02(aB.w + ad4.w));
    f32x4 vA = { (float)hA[0], (float)hA[1], (float)hA[2], (float)hA[3] };
    f32x4 vB = { (float)hB[0], (float)hB[1], (float)hB[2], (float)hB[3] };
    den += (f32x4){ fA.x + fB.x, fA.y + fB.y, fA.z + fB.z, fA.w + fB.w };
    acc0 += fA.x * vA + fB.x * vB;
    acc1 += fA.y * vA + fB.y * vB;
    acc2 += fA.z * vA + fB.z * vB;
    acc3 += fA.w * vA + fB.w * vB;
  }
  if (e + 4 <= e1){
    int eA = e + slot;
    int sA = col[eA];
    float4 aA = *(const float4*)&asrc[sA * 4];
    f16x4 hA = *(const f16x4*)(xb + (size_t)sA * 64);
    float4 fA;
    fA.x = __expf(lrelu02(aA.x + ad4.x)); fA.y = __expf(lrelu02(aA.y + ad4.y));
    fA.z = __expf(lrelu02(aA.z + ad4.z)); fA.w = __expf(lrelu02(aA.w + ad4.w));
    f32x4 vA = { (float)hA[0], (float)hA[1], (float)hA[2], (float)hA[3] };
    den += (f32x4){ fA.x, fA.y, fA.z, fA.w };
    acc0 += fA.x * vA; acc1 += fA.y * vA; acc2 += fA.z * vA; acc3 += fA.w * vA;
    e += 4;
  }
  {
    int eA = e + slot;
    if (eA < e1){
      int sA = col[eA];
      float4 aA = *(const float4*)&asrc[sA * 4];
      f16x4 hA = *(const f16x4*)(xb + (size_t)sA * 64);
      float4 fA;
      fA.x = __expf(lrelu02(aA.x + ad4.x)); fA.y = __expf(lrelu02(aA.y + ad4.y));
      fA.z = __expf(lrelu02(aA.z + ad4.z)); fA.w = __expf(lrelu02(aA.w + ad4.w));
      f32x4 vA = { (float)hA[0], (float)hA[1], (float)hA[2], (float)hA[3] };
      den += (f32x4){ fA.x, fA.y, fA.z, fA.w };
      acc0 += fA.x * vA; acc1 += fA.y * vA; acc2 += fA.z * vA; acc3 += fA.w * vA;
    }
  }

  #pragma unroll
  for (int off = 16; off <= 32; off <<= 1){
    acc0 += shflx4(acc0, off);
    acc1 += shflx4(acc1, off);
    acc2 += shflx4(acc2, off);
    acc3 += shflx4(acc3, off);
    den  += shflx4(den,  off);
  }

  float4 a4 = *(const float4*)&asrc[d * 4];
  float es0 = __expf(lrelu02(a4.x + ad4.x));
  float es1 = __expf(lrelu02(a4.y + ad4.y));
  float es2 = __expf(lrelu02(a4.z + ad4.z));
  float es3 = __expf(lrelu02(a4.w + ad4.w));
  f16x4 hs = *(const f16x4*)(xh + (size_t)d * 64 + cpos);
  f32x4 vs = { (float)hs[0], (float)hs[1], (float)hs[2], (float)hs[3] };
  acc0 += es0 * vs; acc1 += es1 * vs; acc2 += es2 * vs; acc3 += es3 * vs;
  den += (f32x4){ es0, es1, es2, es3 };

  if (slot == 0){
    float i0 = 1.f / (den[0] + 1e-16f), i1 = 1.f / (den[1] + 1e-16f);
    float i2 = 1.f / (den[2] + 1e-16f), i3 = 1.f / (den[3] + 1e-16f);
    _Float16* ob = agg + (size_t)d * 256 + cpos;
    f16x4 o0 = { (_Float16)(acc0[0]*i0), (_Float16)(acc0[1]*i0), (_Float16)(acc0[2]*i0), (_Float16)(acc0[3]*i0) };
    f16x4 o1 = { (_Float16)(acc1[0]*i1), (_Float16)(acc1[1]*i1), (_Float16)(acc1[2]*i1), (_Float16)(acc1[3]*i1) };
    f16x4 o2 = { (_Float16)(acc2[0]*i2), (_Float16)(acc2[1]*i2), (_Float16)(acc2[2]*i2), (_Float16)(acc2[3]*i2) };
    f16x4 o3 = { (_Float16)(acc3[0]*i3), (_Float16)(acc3[1]*i3), (_Float16)(acc3[2]*i3), (_Float16)(acc3[3]*i3) };
    *(f16x4*)(ob)       = o0;
    *(f16x4*)(ob + 64)  = o1;
    *(f16x4*)(ob + 128) = o2;
    *(f16x4*)(ob + 192) = o3;
  }
}

// ---------------- layer-1 aggregate (4 heads, 256ch), fused exp, unroll 4 ----------------

__global__ __launch_bounds__(256) void gat_aggregate4(const _Float16* __restrict__ hH, const float* __restrict__ asrc,
                                                       const float* __restrict__ adst,
                                                       const int* __restrict__ row_ptr, const int* __restrict__ col,
                                                       const float* __restrict__ bias, _Float16* __restrict__ out){
  int lane = threadIdx.x & 63;
  int wid = threadIdx.x >> 6;
  int d = blockIdx.x * 4 + wid;
  if (d >= NODES) return;
  int q = lane >> 4;
  int co = lane * 4;

  float adq = adst[d * 4 + q];

  float ex = __expf(lrelu02(asrc[d * 4 + q] + adq));
  f16x4 hv = *(const f16x4*)(hH + (size_t)d * 256 + co);
  float4 acc = make_float4(ex * (float)hv[0], ex * (float)hv[1], ex * (float)hv[2], ex * (float)hv[3]);
  float den = ex;

  int e0 = row_ptr[d], e1 = row_ptr[d + 1];
  const _Float16* hbase = hH + co;
  int e = e0;
  for (; e + 4 <= e1; e += 4){
    int s0 = col[e], s1 = col[e + 1], s2 = col[e + 2], s3 = col[e + 3];
    float a0 = asrc[s0 * 4 + q], a1 = asrc[s1 * 4 + q], a2 = asrc[s2 * 4 + q], a3 = asrc[s3 * 4 + q];
    f16x4 h0 = *(const f16x4*)(hbase + (size_t)s0 * 256);
    f16x4 h1 = *(const f16x4*)(hbase + (size_t)s1 * 256);
    f16x4 h2 = *(const f16x4*)(hbase + (size_t)s2 * 256);
    f16x4 h3 = *(const f16x4*)(hbase + (size_t)s3 * 256);
    float x0 = __expf(lrelu02(a0 + adq));
    float x1 = __expf(lrelu02(a1 + adq));
    float x2 = __expf(lrelu02(a2 + adq));
    float x3 = __expf(lrelu02(a3 + adq));
    den += x0 + x1 + x2 + x3;
    acc.x += x0 * (float)h0[0] + x1 * (float)h1[0] + x2 * (float)h2[0] + x3 * (float)h3[0];
    acc.y += x0 * (float)h0[1] + x1 * (float)h1[1] + x2 * (float)h2[1] + x3 * (float)h3[1];
    acc.z += x0 * (float)h0[2] + x1 * (float)h1[2] + x2 * (float)h2[2] + x3 * (float)h3[2];
    acc.w += x0 * (float)h0[3] + x1 * (float)h1[3] + x2 * (float)h2[3] + x3 * (float)h3[3];
  }
  for (; e < e1; e++){
    int s0 = col[e];
    float a0 = asrc[s0 * 4 + q];
    f16x4 h0 = *(const f16x4*)(hbase + (size_t)s0 * 256);
    float x0 = __expf(lrelu02(a0 + adq));
    den += x0;
    acc.x += x0 * (float)h0[0]; acc.y += x0 * (float)h0[1];
    acc.z += x0 * (float)h0[2]; acc.w += x0 * (float)h0[3];
  }

  float inv = 1.f / (den + 1e-16f);
  float4 b4 = *(const float4*)&bias[co];
  float4 o = make_float4(acc.x * inv + b4.x, acc.y * inv + b4.y, acc.z * inv + b4.z, acc.w * inv + b4.w);
  o.x = o.x > 0.f ? o.x : expm1f(o.x);
  o.y = o.y > 0.f ? o.y : expm1f(o.y);
  o.z = o.z > 0.f ? o.z : expm1f(o.z);
  o.w = o.w > 0.f ? o.w : expm1f(o.w);
  f16x4 oh = { (_Float16)o.x, (_Float16)o.y, (_Float16)o.z, (_Float16)o.w };
  *(f16x4*)(out + (size_t)d * 256 + co) = oh;
}

// ---------------- layer-2 aggregate (1 head, 64ch): 4 edge-slots x 16 lanes, inline exp ----------------

__global__ __launch_bounds__(256) void gat_aggregate1n(const _Float16* __restrict__ hH,
                                                        const float* __restrict__ asrc, const float* __restrict__ adst,
                                                        const int* __restrict__ row_ptr, const int* __restrict__ col,
                                                        const float* __restrict__ bias, float* __restrict__ out){
  int lane = threadIdx.x & 63;
  int wid = threadIdx.x >> 6;
  int d = blockIdx.x * 4 + wid;
  if (d >= NODES) return;
  int slot = lane >> 4;
  int cpos = (lane & 15) * 4;

  float adq = adst[d];
  f32x4 acc = {0,0,0,0};
  float den = 0.f;

  int e0 = row_ptr[d], e1 = row_ptr[d + 1];
  const _Float16* hb = hH + cpos;
  int e = e0;
  for (; e + 8 <= e1; e += 8){
    int eA = e + slot, eB = e + 4 + slot;
    int sA = col[eA], sB = col[eB];
    float fA = __expf(lrelu02(asrc[sA] + adq));
    float fB = __expf(lrelu02(asrc[sB] + adq));
    f16x4 hA = *(const f16x4*)(hb + (size_t)sA * 64);
    f16x4 hB = *(const f16x4*)(hb + (size_t)sB * 64);
    f32x4 vA = { (float)hA[0], (float)hA[1], (float)hA[2], (float)hA[3] };
    f32x4 vB = { (float)hB[0], (float)hB[1], (float)hB[2], (float)hB[3] };
    den += fA + fB;
    acc += fA * vA + fB * vB;
  }
  if (e + 4 <= e1){
    int eA = e + slot;
    int sA = col[eA];
    float fA = __expf(lrelu02(asrc[sA] + adq));
    f16x4 hA = *(const f16x4*)(hb + (size_t)sA * 64);
    f32x4 vA = { (float)hA[0], (float)hA[1], (float)hA[2], (float)hA[3] };
    den += fA; acc += fA * vA;
    e += 4;
  }
  {
    int eA = e + slot;
    if (eA < e1){
      int sA = col[eA];
      float fA = __expf(lrelu02(asrc[sA] + adq));
      f16x4 hA = *(const f16x4*)(hb + (size_t)sA * 64);
      f32x4 vA = { (float)hA[0], (float)hA[1], (float)hA[2], (float)hA[3] };
      den += fA; acc += fA * vA;
    }
  }

  #pragma unroll
  for (int off = 16; off <= 32; off <<= 1){
    acc += shflx4(acc, off);
    den += __shfl_xor(den, off);
  }

  float es = __expf(lrelu02(asrc[d] + adq));
  f16x4 hs = *(const f16x4*)(hH + (size_t)d * 64 + cpos);
  f32x4 vs = { (float)hs[0], (float)hs[1], (float)hs[2], (float)hs[3] };
  acc += es * vs;
  den += es;

  if (slot == 0){
    float inv = 1.f / (den + 1e-16f);
    float4 b4 = *(const float4*)&bias[cpos];
    float4 o = make_float4(acc[0] * inv + b4.x, acc[1] * inv + b4.y, acc[2] * inv + b4.z, acc[3] * inv + b4.w);
    *(float4*)(out + (size_t)d * 64 + cpos) = o;
  }
}

// ---------------- launch ----------------

extern "C" void kernel_launch(void* const* d_in, const int* in_sizes, int n_in,
                              void* d_out, int out_size, void* d_ws, size_t ws_size,
                              hipStream_t stream) {
  const float* x   = (const float*)d_in[0];
  const int*   ei  = (const int*)  d_in[1];
  const float* W0  = (const float*)d_in[2];
  const float* as0 = (const float*)d_in[3];
  const float* ad0 = (const float*)d_in[4];
  const float* b0  = (const float*)d_in[5];
  const float* W1  = (const float*)d_in[6];
  const float* as1 = (const float*)d_in[7];
  const float* ad1 = (const float*)d_in[8];
  const float* b1  = (const float*)d_in[9];
  const float* W2  = (const float*)d_in[10];
  const float* as2 = (const float*)d_in[11];
  const float* ad2 = (const float*)d_in[12];
  const float* b2  = (const float*)d_in[13];
  float* out = (float*)d_out;

  auto al = [](size_t v){ return (v + 255) & ~(size_t)255; };
  char* p = (char*)d_ws;
  int*      row_ptr = (int*)p;      p += al((NODES + 1) * sizeof(int));
  int*      cnt     = (int*)p;      p += al(NODES * sizeof(int));
  int*      bsums   = (int*)p;      p += al(64 * sizeof(int));
  int*      col     = (int*)p;      p += al(EDGES * sizeof(int));
  float*    asrc    = (float*)p;    p += al(NODES * 4 * sizeof(float));
  float*    adst    = (float*)p;    p += al(NODES * 4 * sizeof(float));
  _Float16* xh      = (_Float16*)p; p += al((size_t)NODES * 64 * sizeof(_Float16));
  _Float16* hH      = (_Float16*)p; p += al((size_t)NODES * 256 * sizeof(_Float16));
  _Float16* actb    = (_Float16*)p; p += al((size_t)NODES * 256 * sizeof(_Float16));
  _Float16* Wt0     = (_Float16*)p; p += al(256 * 64 * sizeof(_Float16));
  _Float16* Wt1     = (_Float16*)p; p += al(256 * 256 * sizeof(_Float16));
  _Float16* Wt2     = (_Float16*)p; p += al(64 * 256 * sizeof(_Float16));
  float*    ws0     = (float*)p;    p += al(256 * sizeof(float));
  float*    wd0     = (float*)p;    p += al(256 * sizeof(float));

  // ---- fused prep (+ zero cnt) ----
  gat_prep<<<3898, 256, 0, stream>>>(x, xh, W0, W1, W2, Wt0, Wt1, Wt2, as0, ad0, ws0, wd0, cnt);

  // ---- CSR build (by dst) ----
  gat_hist<<<(EDGES + 255) / 256, 256, 0, stream>>>(ei, cnt);
  gat_blocksum<<<NB_SCAN, 256, 0, stream>>>(cnt, bsums);
  gat_rowptr<<<NB_SCAN, 256, 0, stream>>>(cnt, bsums, row_ptr);
  gat_scatter<<<(EDGES + 255) / 256, 256, 0, stream>>>(ei, row_ptr, cnt, col);

  const int nodeBlocks = (NODES + 3) / 4;
  const int gemmBlocks = (NODES + 63) / 64;

  // ---- Layer 0: attn in input space; aggregate x (64-dim, inline slot-amortized exp) -> hH ----
  gat_attn0<<<nodeBlocks, 256, 0, stream>>>(xh, ws0, wd0, asrc, adst, NODES);
  gat_aggregate_in64<<<nodeBlocks, 256, 0, stream>>>(xh, asrc, adst, row_ptr, col, hH);

  // ---- Fused: (agg @ Wt0 + b0 + ELU) @ W1 -> actb, + layer-1 attn coefficients ----
  gat_gemm_l0l1<<<gemmBlocks, 256, 0, stream>>>(hH, Wt0, b0, Wt1, actb, as1, ad1, asrc, adst, NODES);

  // ---- Layer 1 aggregate: actb -> hH ----
  gat_aggregate4<<<nodeBlocks, 256, 0, stream>>>(actb, asrc, adst, row_ptr, col, b1, hH);

  // ---- Layer 2: hH @ W2 -> actb (64ch, + attn1); aggregate -> out ----
  gat_gemm_mfma1<256, 64><<<gemmBlocks, 256, 0, stream>>>(hH, Wt2, actb, as2, ad2, asrc, adst, NODES);
  gat_aggregate1n<<<nodeBlocks, 256, 0, stream>>>(actb, asrc, adst, row_ptr, col, b2, out);
}